// Round 15
// baseline (315.553 us; speedup 1.0000x reference)
//
#include <hip/hip_runtime.h>
#include <math.h>

// Shapes: B=4096, IN=1024, H=1024, S=64, Q=16, OUT=1024
// ws layout:
//   [16,32MB)   A2 f16 [4096][2048]  (cols 0-1023 = h_int f16, 1024-2047 = m_t)
//   [32,40MB)   BT f16 [2048][2048]  (= W_og^T)
//   [40,41MB)   Wqs f32 [1025][64]
//   [41MB)      idx int[4096]; counter; list
//   [42,58MB)   A1 f16 [4096][2048]  ([x|h] converted)
//   [58,62MB)   BTin f16 [1024][2048] (W_in^T)
//   [62,78MB)   fix_scratch f32 [FIX_CAP][1024]

typedef __attribute__((ext_vector_type(4))) float floatx4;
typedef __attribute__((ext_vector_type(8))) _Float16 half8;
typedef __attribute__((ext_vector_type(4))) _Float16 half4;

#define OUT_H_OFF 4194304
#define TAU 4e-3f
#define FIX_CAP 512

#define AS1 __attribute__((address_space(1)))
#define AS3 __attribute__((address_space(3)))
#define GLL(gptr, lptr) __builtin_amdgcn_global_load_lds((const AS1 void*)(gptr), (AS3 void*)(lptr), 16, 0, 0)

__device__ __forceinline__ _Float16 f2h(float f) { return (_Float16)f; }  // v_cvt_f16_f32, RNE

// ---------------- K1: BT[n][k] = f16(W_og[k][n]), 2048x2048 ----------------
__global__ __launch_bounds__(256) void k_transpose(const float* __restrict__ W,
                                                   _Float16* __restrict__ BT) {
  __shared__ float tile[64][65];
  const int k0 = blockIdx.x * 64, n0 = blockIdx.y * 64;
  const int t = threadIdx.x, c = t & 63, rr = t >> 6;
#pragma unroll
  for (int i = 0; i < 16; ++i) {
    int r = i * 4 + rr;
    tile[r][c] = W[(size_t)(k0 + r) * 2048 + n0 + c];
  }
  __syncthreads();
#pragma unroll
  for (int i = 0; i < 16; ++i) {
    int r = i * 4 + rr;  // n-local
    BT[(size_t)(n0 + r) * 2048 + k0 + c] = f2h(tile[c][r]);
  }
}

// ---------------- K1b: convert A = [x|h] -> A1 f16 [4096][2048] --------
__global__ __launch_bounds__(256) void k_convA(const float* __restrict__ x_t, const float* __restrict__ h_prev,
                                               _Float16* __restrict__ A1) {
  const int stride = gridDim.x * blockDim.x;
  for (int c = blockIdx.x * blockDim.x + threadIdx.x; c < 2097152; c += stride) {
    int m = c >> 9, kc = (c & 511) << 2;
    const float* src = (kc < 1024) ? (x_t + (size_t)m * 1024 + kc)
                                   : (h_prev + (size_t)m * 1024 + (kc - 1024));
    floatx4 v = *reinterpret_cast<const floatx4*>(src);
    half4 h = {f2h(v[0]), f2h(v[1]), f2h(v[2]), f2h(v[3])};
    *reinterpret_cast<half4*>(&A1[(size_t)m * 2048 + kc]) = h;
  }
}

// ------- K1c: convert+transpose W_in [2048][1024] -> BTin f16 [1024][2048] -------
__global__ __launch_bounds__(256) void k_convB(const float* __restrict__ W_in,
                                               _Float16* __restrict__ BTin) {
  __shared__ float tile[64][65];
  const int k0 = blockIdx.x * 64, n0 = blockIdx.y * 64;
  const int t = threadIdx.x, c = t & 63, rr = t >> 6;
#pragma unroll
  for (int i = 0; i < 16; ++i) {
    int r = i * 4 + rr;
    tile[r][c] = W_in[(size_t)(k0 + r) * 1024 + n0 + c];
  }
  __syncthreads();
#pragma unroll
  for (int i = 0; i < 16; ++i) {
    int r = i * 4 + rr;  // n-local
    BTin[(size_t)(n0 + r) * 2048 + k0 + c] = f2h(tile[c][r]);
  }
}

// -------- K2h: A2[:, :1024] = f16(tanh(A1 @ W_in + b_in)), fp16 MFMA --------
// BM=128, BN=64, BK=32. A operand DIRECT global->reg (coalesced 16 lines/wave,
// double-buffered, prefetch 1 step); B via GLL->LDS 2-buf. LDS/block-step 40->16KB.
__global__ __launch_bounds__(256) void k_gemm1h(const _Float16* __restrict__ A1,
                                                const _Float16* __restrict__ BTin,
                                                const float* __restrict__ b_in,
                                                _Float16* __restrict__ A2) {
  __shared__ __align__(16) _Float16 Bs[2 * 2048];  // [buf][64*32] = 8KB
  const int t = threadIdx.x;
  const int lane = t & 63, w = t >> 6;
  const int wm = w >> 1, wn = w & 1;
  const int m0 = blockIdx.x * 128, n0 = blockIdx.y * 64;
  const int lr = lane & 15, lk = lane >> 4;
  floatx4 acc[4][2];
  floatx4 zero = {0.f, 0.f, 0.f, 0.f};
#pragma unroll
  for (int mi = 0; mi < 4; ++mi)
#pragma unroll
    for (int ni = 0; ni < 2; ++ni) acc[mi][ni] = zero;

  // per-wave A base row addresses (lane-resident)
  const _Float16* Abase[4];
#pragma unroll
  for (int mi = 0; mi < 4; ++mi)
    Abase[mi] = A1 + (size_t)(m0 + wm * 64 + mi * 16 + lr) * 2048 + lk * 8;

  auto stageB = [&](int p, int kt) {   // 1 GLL per thread
    const int k0 = kt * 32;
    int cc = t;
    int row = cc >> 2, sl = cc & 3;
    int sg = sl ^ ((row >> 1) & 3);
    size_t gb = (size_t)(n0 + row) * 2048 + k0 + sg * 8;
    GLL(BTin + gb, &Bs[p * 2048 + cc * 8]);
  };
  auto loadA = [&](half8* af, int kt) {
    const int k0 = kt * 32;
#pragma unroll
    for (int mi = 0; mi < 4; ++mi)
      af[mi] = *reinterpret_cast<const half8*>(Abase[mi] + k0);
  };
  auto compute = [&](int p, const half8* af) {
    half8 bf[2];
#pragma unroll
    for (int ni = 0; ni < 2; ++ni) {
      int row = wn * 32 + ni * 16 + lr;
      int sl = lk ^ ((row >> 1) & 3);
      bf[ni] = *reinterpret_cast<const half8*>(&Bs[p * 2048 + row * 32 + sl * 8]);
    }
#pragma unroll
    for (int mi = 0; mi < 4; ++mi)
#pragma unroll
      for (int ni = 0; ni < 2; ++ni)
        acc[mi][ni] = __builtin_amdgcn_mfma_f32_16x16x32_f16(af[mi], bf[ni], acc[mi][ni], 0, 0, 0);
  };

  half8 afA[4], afB[4];
  stageB(0, 0);
  loadA(afA, 0);
  __syncthreads();
  for (int kt2 = 0; kt2 < 64; kt2 += 2) {
    // even step kt2 (buf0, afA); prefetch kt2+1 (buf1, afB)
    stageB(1, kt2 + 1);
    loadA(afB, kt2 + 1);
    compute(0, afA);
    __syncthreads();
    if (kt2 + 2 < 64) {
      stageB(0, kt2 + 2);
      loadA(afA, kt2 + 2);
    }
    compute(1, afB);
    __syncthreads();
  }

#pragma unroll
  for (int mi = 0; mi < 4; ++mi) {
#pragma unroll
    for (int ni = 0; ni < 2; ++ni) {
      int gn = n0 + wn * 32 + ni * 16 + lr;
      float bias = b_in[gn];
      int gmb = m0 + wm * 64 + mi * 16 + lk * 4;
#pragma unroll
      for (int j = 0; j < 4; ++j) {
        int gm = gmb + j;
        A2[(size_t)gm * 2048 + gn] = f2h(tanhf(acc[mi][ni][j] + bias));
      }
    }
  }
}

// ---------------- K2f: fp32 fallback GEMM1 (used when ws too small) ----------------
__global__ __launch_bounds__(256) void k_gemm1(const float* __restrict__ x_t, const float* __restrict__ h_prev,
                                               const float* __restrict__ W_in, const float* __restrict__ b_in,
                                               _Float16* __restrict__ A2) {
  __shared__ float As[16 * 128];
  __shared__ float Bs[16 * 64];
  const int t = threadIdx.x;
  const int m0 = blockIdx.x * 128, n0 = blockIdx.y * 64;
  const int ty = t >> 4, tx = t & 15;
  float acc[8][4];
#pragma unroll
  for (int i = 0; i < 8; ++i)
#pragma unroll
    for (int j = 0; j < 4; ++j) acc[i][j] = 0.f;
  for (int kt = 0; kt < 128; ++kt) {
    const int k0 = kt * 16;
    __syncthreads();
#pragma unroll
    for (int u = 0; u < 2; ++u) {
      int cc = t + u * 256;
      int row = cc >> 2, col4 = (cc & 3) << 2;
      int gk = k0 + col4;
      const float* src = (gk < 1024) ? (x_t + (size_t)(m0 + row) * 1024 + gk)
                                     : (h_prev + (size_t)(m0 + row) * 1024 + (gk - 1024));
      floatx4 v = *reinterpret_cast<const floatx4*>(src);
      As[(col4 + 0) * 128 + row] = v[0];
      As[(col4 + 1) * 128 + row] = v[1];
      As[(col4 + 2) * 128 + row] = v[2];
      As[(col4 + 3) * 128 + row] = v[3];
    }
    {
      int kr = t >> 4, c4 = (t & 15) << 2;
      *reinterpret_cast<floatx4*>(&Bs[kr * 64 + c4]) =
          *reinterpret_cast<const floatx4*>(&W_in[(size_t)(k0 + kr) * 1024 + n0 + c4]);
    }
    __syncthreads();
#pragma unroll
    for (int kk = 0; kk < 16; ++kk) {
      floatx4 a0 = *reinterpret_cast<const floatx4*>(&As[kk * 128 + ty * 8]);
      floatx4 a1 = *reinterpret_cast<const floatx4*>(&As[kk * 128 + ty * 8 + 4]);
      floatx4 b = *reinterpret_cast<const floatx4*>(&Bs[kk * 64 + tx * 4]);
#pragma unroll
      for (int j = 0; j < 4; ++j) {
        acc[0][j] += a0[0] * b[j]; acc[1][j] += a0[1] * b[j];
        acc[2][j] += a0[2] * b[j]; acc[3][j] += a0[3] * b[j];
        acc[4][j] += a1[0] * b[j]; acc[5][j] += a1[1] * b[j];
        acc[6][j] += a1[2] * b[j]; acc[7][j] += a1[3] * b[j];
      }
    }
  }
  const int nbase = n0 + tx * 4;
  floatx4 bias = *reinterpret_cast<const floatx4*>(&b_in[nbase]);
#pragma unroll
  for (int i = 0; i < 8; ++i) {
    int gm = m0 + ty * 8 + i;
    half4 pk;
#pragma unroll
    for (int j = 0; j < 4; ++j) pk[j] = f2h(tanhf(acc[i][j] + bias[j]));
    *reinterpret_cast<half4*>(&A2[(size_t)gm * 2048 + nbase]) = pk;
  }
}

// ---------------- K3: Wqs = W_q @ W_sel (+ fused bias row 1024) ----------------
__global__ __launch_bounds__(256) void k_wqs(const float* __restrict__ W_q, const float* __restrict__ b_q,
                                             const float* __restrict__ W_sel, const float* __restrict__ b_sel,
                                             float* __restrict__ Wqs) {
  const int t = threadIdx.x;
  const int w = t >> 6, lane = t & 63;
  const int h = blockIdx.x * 4 + w;
  if (h > 1024) return;
  const float* src = (h < 1024) ? (W_q + (size_t)h * 1024) : b_q;
  float acc = 0.f;
  for (int j = 0; j < 1024; j += 4) {
    floatx4 v = *reinterpret_cast<const floatx4*>(&src[j]);
    acc += v[0] * W_sel[(j + 0) * 64 + lane];
    acc += v[1] * W_sel[(j + 1) * 64 + lane];
    acc += v[2] * W_sel[(j + 2) * 64 + lane];
    acc += v[3] * W_sel[(j + 3) * 64 + lane];
  }
  if (h == 1024) acc += b_sel[lane];
  Wqs[(size_t)h * 64 + lane] = acc;
}

// ------- K4: logits = h(f16) @ Wqs + bqs; argmax; flag gap<TAU. 16 rows/block -------
__global__ __launch_bounds__(256) void k_argmax(const _Float16* __restrict__ A2, const float* __restrict__ Wqs,
                                                int* __restrict__ idx, int* __restrict__ counter,
                                                int* __restrict__ list, float tau) {
  __shared__ float Ahs[64 * 17];  // [k][r] stride 17
  __shared__ float Wt[64 * 64];   // [k][s]
  const int t = threadIdx.x;
  const int r0 = blockIdx.x * 16;
  const int w = t >> 6, lane = t & 63;
  float acc[4] = {0.f, 0.f, 0.f, 0.f};

  for (int kt = 0; kt < 16; ++kt) {
    const int k0 = kt * 64;
    __syncthreads();
    if (t < 128) {
      int r = t >> 3, k8 = (t & 7) * 8;
      half8 v = *reinterpret_cast<const half8*>(&A2[(size_t)(r0 + r) * 2048 + k0 + k8]);
#pragma unroll
      for (int j = 0; j < 8; ++j) Ahs[(k8 + j) * 17 + r] = (float)v[j];
    }
#pragma unroll
    for (int u = 0; u < 4; ++u) {
      int cc = t + u * 256;
      int kr = cc >> 4, c4 = (cc & 15) << 2;
      *reinterpret_cast<floatx4*>(&Wt[kr * 64 + c4]) =
          *reinterpret_cast<const floatx4*>(&Wqs[(size_t)(k0 + kr) * 64 + c4]);
    }
    __syncthreads();
#pragma unroll
    for (int k = 0; k < 64; ++k) {
      float wv = Wt[k * 64 + lane];
      const float* ar = &Ahs[k * 17 + w * 4];
      acc[0] += ar[0] * wv;
      acc[1] += ar[1] * wv;
      acc[2] += ar[2] * wv;
      acc[3] += ar[3] * wv;
    }
  }
  const float bqs = Wqs[1024 * 64 + lane];
#pragma unroll
  for (int i = 0; i < 4; ++i) {
    float v1 = acc[i] + bqs;
    int i1 = lane;
    float v2 = -__builtin_inff();
#pragma unroll
    for (int off = 32; off >= 1; off >>= 1) {
      float ov1 = __shfl_xor(v1, off);
      int oi1 = __shfl_xor(i1, off);
      float ov2 = __shfl_xor(v2, off);
      if (ov1 > v1 || (ov1 == v1 && oi1 < i1)) {
        v2 = fmaxf(v1, ov2); v1 = ov1; i1 = oi1;
      } else {
        v2 = fmaxf(v2, ov1);
      }
    }
    if (lane == 0) {
      int row = r0 + w * 4 + i;
      idx[row] = i1;
      if (v1 - v2 < tau) {
        int pos = atomicAdd(counter, 1);
        if (pos < FIX_CAP) list[pos] = row;
      }
    }
  }
}

// ------- K4b: batched exact fp32 z, LDS-staged W -------
__global__ __launch_bounds__(256) void k_fixA3(const float* __restrict__ x_t, const float* __restrict__ h_prev,
                                               const float* __restrict__ W_in, const int* __restrict__ counter,
                                               const int* __restrict__ list, float* __restrict__ scratch) {
  __shared__ float Ws[256 * 64];   // [k][col] 64KB
  __shared__ float xr[8][260];
  const int t = threadIdx.x;
  const int cnt = min(counter[0], FIX_CAP);
  const int nbatch = (cnt + 7) >> 3;
  const int col = t & 63;
  const int rp = t >> 6;
  const int gcol = blockIdx.x * 64 + col;
  for (int mb = blockIdx.y; mb < nbatch; mb += gridDim.y) {
    const int rbase = mb * 8;
    float a0[4] = {0.f, 0.f, 0.f, 0.f};
    float a1[4] = {0.f, 0.f, 0.f, 0.f};
    for (int kc = 0; kc < 8; ++kc) {
      __syncthreads();
      {
        int r = t >> 5, kl = (t & 31) * 8;
        int e = rbase + r;
        int row = list[e < cnt ? e : 0];
        int kg = kc * 256 + kl;
        const float* src = (kg < 1024) ? (x_t + (size_t)row * 1024 + kg)
                                       : (h_prev + (size_t)row * 1024 + (kg - 1024));
        floatx4 v0 = *reinterpret_cast<const floatx4*>(src);
        floatx4 v1 = *reinterpret_cast<const floatx4*>(src + 4);
        *reinterpret_cast<floatx4*>(&xr[r][kl]) = v0;
        *reinterpret_cast<floatx4*>(&xr[r][kl + 4]) = v1;
      }
      {
        const float* Wb = W_in + (size_t)(kc * 256) * 1024 + blockIdx.x * 64;
#pragma unroll
        for (int i = 0; i < 16; ++i) {
          int f = t + 256 * i;
          int k = f >> 4, c4 = (f & 15) << 2;
          floatx4 v = *reinterpret_cast<const floatx4*>(Wb + (size_t)k * 1024 + c4);
          *reinterpret_cast<floatx4*>(&Ws[k * 64 + c4]) = v;
        }
      }
      __syncthreads();
      const floatx4* x0v = reinterpret_cast<const floatx4*>(xr[rp * 2]);
      const floatx4* x1v = reinterpret_cast<const floatx4*>(xr[rp * 2 + 1]);
      for (int k4 = 0; k4 < 64; ++k4) {
        floatx4 xv0 = x0v[k4];
        floatx4 xv1 = x1v[k4];
        int kb = k4 * 4;
        float w0 = Ws[(kb + 0) * 64 + col];
        float w1 = Ws[(kb + 1) * 64 + col];
        float w2 = Ws[(kb + 2) * 64 + col];
        float w3 = Ws[(kb + 3) * 64 + col];
        a0[0] += xv0[0] * w0; a1[0] += xv1[0] * w0;
        a0[1] += xv0[1] * w1; a1[1] += xv1[1] * w1;
        a0[2] += xv0[2] * w2; a1[2] += xv1[2] * w2;
        a0[3] += xv0[3] * w3; a1[3] += xv1[3] * w3;
      }
    }
    float z0 = (a0[0] + a0[1]) + (a0[2] + a0[3]);
    float z1 = (a1[0] + a1[1]) + (a1[2] + a1[3]);
    int e0 = rbase + rp * 2, e1 = e0 + 1;
    if (e0 < cnt) scratch[(size_t)e0 * 1024 + gcol] = z0;
    if (e1 < cnt) scratch[(size_t)e1 * 1024 + gcol] = z1;
    __syncthreads();
  }
}

// ------- K4c: block-per-row: h=tanh(z+b) -> logits (ILP-8) -> argmax -> idx -------
__global__ __launch_bounds__(256) void k_fixB(const float* __restrict__ scratch, const float* __restrict__ b_in,
                                              const float* __restrict__ Wqs, const int* __restrict__ counter,
                                              const int* __restrict__ list, int* __restrict__ idx) {
  __shared__ float hrow[1024];
  __shared__ float partial[4 * 64];
  __shared__ float lg[64];
  const int t = threadIdx.x;
  const int cnt = min(counter[0], FIX_CAP);
  const int e = blockIdx.x;
  if (e >= cnt) return;
  const int r = list[e];
  const int n4 = t * 4;
  floatx4 b4 = *reinterpret_cast<const floatx4*>(&b_in[n4]);
  floatx4 z4 = *reinterpret_cast<const floatx4*>(&scratch[(size_t)e * 1024 + n4]);
  hrow[n4 + 0] = tanhf(z4[0] + b4[0]);
  hrow[n4 + 1] = tanhf(z4[1] + b4[1]);
  hrow[n4 + 2] = tanhf(z4[2] + b4[2]);
  hrow[n4 + 3] = tanhf(z4[3] + b4[3]);
  __syncthreads();
  const int s = t & 63, part = t >> 6;
  const int hb0 = part * 256;
  const float* Wp = Wqs + (size_t)hb0 * 64 + s;
  float p0 = 0.f, p1 = 0.f, p2 = 0.f, p3 = 0.f, p4 = 0.f, p5 = 0.f, p6 = 0.f, p7 = 0.f;
  for (int h8 = 0; h8 < 256; h8 += 8) {
    float w0 = Wp[(size_t)(h8 + 0) * 64];
    float w1 = Wp[(size_t)(h8 + 1) * 64];
    float w2 = Wp[(size_t)(h8 + 2) * 64];
    float w3 = Wp[(size_t)(h8 + 3) * 64];
    float w4 = Wp[(size_t)(h8 + 4) * 64];
    float w5 = Wp[(size_t)(h8 + 5) * 64];
    float w6 = Wp[(size_t)(h8 + 6) * 64];
    float w7 = Wp[(size_t)(h8 + 7) * 64];
    const int hb = hb0 + h8;
    p0 += hrow[hb + 0] * w0;
    p1 += hrow[hb + 1] * w1;
    p2 += hrow[hb + 2] * w2;
    p3 += hrow[hb + 3] * w3;
    p4 += hrow[hb + 4] * w4;
    p5 += hrow[hb + 5] * w5;
    p6 += hrow[hb + 6] * w6;
    p7 += hrow[hb + 7] * w7;
  }
  partial[part * 64 + s] = ((p0 + p1) + (p2 + p3)) + ((p4 + p5) + (p6 + p7));
  __syncthreads();
  if (t < 64) lg[t] = partial[t] + partial[64 + t] + partial[128 + t] + partial[192 + t] + Wqs[1024 * 64 + t];
  __syncthreads();
  if (t == 0) {
    float bv = lg[0]; int bi = 0;
    for (int ss = 1; ss < 64; ++ss) {
      if (lg[ss] > bv) { bv = lg[ss]; bi = ss; }
    }
    idx[r] = bi;
  }
}

// ---------------- K5: mixture: angles -> cos -> m_t (block per row, h from A2 f16) --------
__global__ __launch_bounds__(256) void k_mix(const _Float16* __restrict__ A2h, const int* __restrict__ idx,
                                             const float* __restrict__ Wm_enc, const float* __restrict__ theta,
                                             const float* __restrict__ Wm_dec, const float* __restrict__ b_m,
                                             _Float16* __restrict__ A2) {
  __shared__ float hrow[1024];
  __shared__ float partial[256];
  __shared__ float expz[16];
  const int b = blockIdx.x, t = threadIdx.x;
  const int s = idx[b];
  {
    half4 v = *reinterpret_cast<const half4*>(&A2h[(size_t)b * 2048 + t * 4]);
    hrow[t * 4 + 0] = (float)v[0];
    hrow[t * 4 + 1] = (float)v[1];
    hrow[t * 4 + 2] = (float)v[2];
    hrow[t * 4 + 3] = (float)v[3];
  }
  __syncthreads();
  const int q = t & 15, g = t >> 4;
  const float* We = Wm_enc + (size_t)s * 16384;
  float p = 0.f;
#pragma unroll 8
  for (int j = 0; j < 64; ++j) {
    int h = g + j * 16;
    p += hrow[h] * We[h * 16 + q];
  }
  partial[t] = p;
  __syncthreads();
  if (t < 16) {
    float a = 0.f;
#pragma unroll
    for (int g2 = 0; g2 < 16; ++g2) a += partial[g2 * 16 + t];
    a += theta[s * 16 + t];
    expz[t] = cosf(a);
  }
  __syncthreads();
  const float* Wd = Wm_dec + (size_t)s * 16384;
  float e[16];
#pragma unroll
  for (int qq = 0; qq < 16; ++qq) e[qq] = expz[qq];
#pragma unroll
  for (int r = 0; r < 4; ++r) {
    int h = r * 256 + t;
    float v = b_m[h];
#pragma unroll
    for (int qq = 0; qq < 16; ++qq) v += e[qq] * Wd[qq * 1024 + h];
    A2[(size_t)b * 2048 + 1024 + h] = f2h(tanhf(v));
  }
}

// ---------------- K6: goh = A2 @ BT^T + b_og -> tanh/split epilogue, fp16 MFMA ----------------
// 128x128 tile, BK=32. A direct global->reg double-buffered; B GLL->LDS 2-buf.
// LDS/block-step 64->24KB (the R12-measured port bound).
__global__ __launch_bounds__(256) void k_gemm4h(const _Float16* __restrict__ A2,
                                                const _Float16* __restrict__ BT,
                                                const float* __restrict__ b_og, float* __restrict__ out) {
  __shared__ __align__(16) _Float16 Bs[2 * 4096];  // [buf][128*32] = 16KB
  const int t = threadIdx.x;
  const int lane = t & 63, w = t >> 6;
  const int wm = w >> 1, wn = w & 1;
  const int m0 = blockIdx.x * 128, n0 = blockIdx.y * 128;
  const int lr = lane & 15, lk = lane >> 4;
  floatx4 acc[4][4];
  floatx4 zero = {0.f, 0.f, 0.f, 0.f};
#pragma unroll
  for (int mi = 0; mi < 4; ++mi)
#pragma unroll
    for (int ni = 0; ni < 4; ++ni) acc[mi][ni] = zero;

  const _Float16* Abase[4];
#pragma unroll
  for (int mi = 0; mi < 4; ++mi)
    Abase[mi] = A2 + (size_t)(m0 + wm * 64 + mi * 16 + lr) * 2048 + lk * 8;

  auto stageB = [&](int p, int kt) {   // 2 GLL per thread
    const int k0 = kt * 32;
#pragma unroll
    for (int j = 0; j < 2; ++j) {
      int cc = j * 256 + t;
      int row = cc >> 2, sl = cc & 3;
      int sg = sl ^ ((row >> 1) & 3);
      size_t gb = (size_t)(n0 + row) * 2048 + k0 + sg * 8;
      GLL(BT + gb, &Bs[p * 4096 + cc * 8]);
    }
  };
  auto loadA = [&](half8* af, int kt) {
    const int k0 = kt * 32;
#pragma unroll
    for (int mi = 0; mi < 4; ++mi)
      af[mi] = *reinterpret_cast<const half8*>(Abase[mi] + k0);
  };
  auto compute = [&](int p, const half8* af) {
    half8 bf[4];
#pragma unroll
    for (int ni = 0; ni < 4; ++ni) {
      int row = wn * 64 + ni * 16 + lr;
      int sl = lk ^ ((row >> 1) & 3);
      bf[ni] = *reinterpret_cast<const half8*>(&Bs[p * 4096 + row * 32 + sl * 8]);
    }
#pragma unroll
    for (int mi = 0; mi < 4; ++mi)
#pragma unroll
      for (int ni = 0; ni < 4; ++ni)
        acc[mi][ni] = __builtin_amdgcn_mfma_f32_16x16x32_f16(af[mi], bf[ni], acc[mi][ni], 0, 0, 0);
  };

  half8 afA[4], afB[4];
  stageB(0, 0);
  loadA(afA, 0);
  __syncthreads();
  for (int kt2 = 0; kt2 < 64; kt2 += 2) {
    stageB(1, kt2 + 1);
    loadA(afB, kt2 + 1);
    compute(0, afA);
    __syncthreads();
    if (kt2 + 2 < 64) {
      stageB(0, kt2 + 2);
      loadA(afA, kt2 + 2);
    }
    compute(1, afB);
    __syncthreads();
  }

#pragma unroll
  for (int mi = 0; mi < 4; ++mi) {
#pragma unroll
    for (int ni = 0; ni < 4; ++ni) {
      int gn = n0 + wn * 64 + ni * 16 + lr;
      float bias = b_og[gn];
      int gmb = m0 + wm * 64 + mi * 16 + lk * 4;
#pragma unroll
      for (int j = 0; j < 4; ++j) {
        int gm = gmb + j;
        float v = acc[mi][ni][j] + bias;
        if (gn < 1024) {
          out[OUT_H_OFF + (size_t)gm * 1024 + gn] = tanhf(v);  // h_next
        } else {
          out[(size_t)gm * 1024 + (gn - 1024)] = v;            // y_t
        }
      }
    }
  }
}

extern "C" void kernel_launch(void* const* d_in, const int* in_sizes, int n_in,
                              void* d_out, int out_size, void* d_ws, size_t ws_size,
                              hipStream_t stream) {
  (void)in_sizes; (void)n_in; (void)out_size;
  const float* x_t    = (const float*)d_in[0];
  const float* h_prev = (const float*)d_in[1];
  const float* W_in   = (const float*)d_in[2];
  const float* b_in   = (const float*)d_in[3];
  const float* W_q    = (const float*)d_in[4];
  const float* b_q    = (const float*)d_in[5];
  const float* W_sel  = (const float*)d_in[6];
  const float* b_sel  = (const float*)d_in[7];
  const float* Wm_enc = (const float*)d_in[8];
  const float* theta  = (const float*)d_in[9];
  const float* Wm_dec = (const float*)d_in[10];
  const float* b_m    = (const float*)d_in[11];
  const float* W_og   = (const float*)d_in[12];
  const float* b_og   = (const float*)d_in[13];
  float* out = (float*)d_out;

  char* ws = (char*)d_ws;
  _Float16* A2          = (_Float16*)(ws + ((size_t)16 << 20));
  _Float16* BT          = (_Float16*)(ws + ((size_t)32 << 20));
  float* Wqs            = (float*)(ws + ((size_t)40 << 20));
  int* idx              = (int*)(ws + ((size_t)41 << 20));
  int* counter          = (int*)(ws + ((size_t)41 << 20) + 16384);
  int* list             = (int*)(ws + ((size_t)41 << 20) + 16384 + 64);
  _Float16* A1          = (_Float16*)(ws + ((size_t)42 << 20));
  _Float16* BTin        = (_Float16*)(ws + ((size_t)58 << 20));
  float* fix_scratch    = (float*)(ws + ((size_t)62 << 20));

  const bool use_mfma = ws_size >= ((size_t)82 << 20);

  hipLaunchKernelGGL(k_transpose, dim3(32, 32), dim3(256), 0, stream, W_og, BT);
  hipLaunchKernelGGL(k_wqs, dim3(257), dim3(256), 0, stream, W_q, b_q, W_sel, b_sel, Wqs);
  hipMemsetAsync(counter, 0, 4, stream);

  if (use_mfma) {
    hipLaunchKernelGGL(k_convA, dim3(2048), dim3(256), 0, stream, x_t, h_prev, A1);
    hipLaunchKernelGGL(k_convB, dim3(32, 16), dim3(256), 0, stream, W_in, BTin);
    hipLaunchKernelGGL(k_gemm1h, dim3(32, 16), dim3(256), 0, stream,
                       A1, BTin, b_in, A2);
    hipLaunchKernelGGL(k_argmax, dim3(256), dim3(256), 0, stream, A2, Wqs, idx, counter, list, TAU);
    hipLaunchKernelGGL(k_fixA3, dim3(16, 32), dim3(256), 0, stream,
                       x_t, h_prev, W_in, counter, list, fix_scratch);
    hipLaunchKernelGGL(k_fixB, dim3(FIX_CAP), dim3(256), 0, stream,
                       fix_scratch, b_in, Wqs, counter, list, idx);
  } else {
    hipLaunchKernelGGL(k_gemm1, dim3(32, 16), dim3(256), 0, stream, x_t, h_prev, W_in, b_in, A2);
    hipLaunchKernelGGL(k_argmax, dim3(256), dim3(256), 0, stream, A2, Wqs, idx, counter, list, 0.0f);
  }

  hipLaunchKernelGGL(k_mix, dim3(4096), dim3(256), 0, stream, A2, idx, Wm_enc, theta, Wm_dec, b_m, A2);
  hipLaunchKernelGGL(k_gemm4h, dim3(32, 16), dim3(256), 0, stream, A2, BT, b_og, out);
}

// Round 16
// 275.940 us; speedup vs baseline: 1.1436x; 1.1436x over previous
//
#include <hip/hip_runtime.h>
#include <math.h>

// Shapes: B=4096, IN=1024, H=1024, S=64, Q=16, OUT=1024
// ws layout:
//   [16,32MB)   A2 f16 [4096][2048]  (cols 0-1023 = h_int f16, 1024-2047 = m_t)
//   [32,40MB)   BT f16 [2048][2048]  (= W_og^T)
//   [40,41MB)   Wqs f32 [1025][64]
//   [41MB)      idx int[4096]; counter; list
//   [42,58MB)   A1 f16 [4096][2048]  ([x|h] converted)
//   [58,62MB)   BTin f16 [1024][2048] (W_in^T)
//   [62,78MB)   fix_scratch f32 [FIX_CAP][1024]

typedef __attribute__((ext_vector_type(4))) float floatx4;
typedef __attribute__((ext_vector_type(8))) _Float16 half8;
typedef __attribute__((ext_vector_type(4))) _Float16 half4;

#define OUT_H_OFF 4194304
#define TAU 4e-3f
#define FIX_CAP 512

#define AS1 __attribute__((address_space(1)))
#define AS3 __attribute__((address_space(3)))
#define GLL(gptr, lptr) __builtin_amdgcn_global_load_lds((const AS1 void*)(gptr), (AS3 void*)(lptr), 16, 0, 0)

__device__ __forceinline__ _Float16 f2h(float f) { return (_Float16)f; }  // v_cvt_f16_f32, RNE

// ---- K0 prep (fused): [0,1024) transpose W_og; [1024,1536) convB; [1536,3584) convA;
//      [3584,3841) wqs. Branch is block-uniform -> per-body __syncthreads is safe.
__global__ __launch_bounds__(256) void k_prep(const float* __restrict__ W_og, _Float16* __restrict__ BT,
                                              const float* __restrict__ W_in, _Float16* __restrict__ BTin,
                                              const float* __restrict__ x_t, const float* __restrict__ h_prev,
                                              _Float16* __restrict__ A1,
                                              const float* __restrict__ W_q, const float* __restrict__ b_q,
                                              const float* __restrict__ W_sel, const float* __restrict__ b_sel,
                                              float* __restrict__ Wqs) {
  const int bid = blockIdx.x;
  const int t = threadIdx.x;
  if (bid < 1024) {            // ---- transpose W_og [2048][2048] -> BT f16
    __shared__ float tile[64][65];
    const int k0 = (bid & 31) * 64, n0 = (bid >> 5) * 64;
    const int c = t & 63, rr = t >> 6;
#pragma unroll
    for (int i = 0; i < 16; ++i) {
      int r = i * 4 + rr;
      tile[r][c] = W_og[(size_t)(k0 + r) * 2048 + n0 + c];
    }
    __syncthreads();
#pragma unroll
    for (int i = 0; i < 16; ++i) {
      int r = i * 4 + rr;
      BT[(size_t)(n0 + r) * 2048 + k0 + c] = f2h(tile[c][r]);
    }
  } else if (bid < 1536) {     // ---- transpose+convert W_in [2048][1024] -> BTin f16
    __shared__ float tile[64][65];
    const int id = bid - 1024;
    const int k0 = (id & 31) * 64, n0 = (id >> 5) * 64;
    const int c = t & 63, rr = t >> 6;
#pragma unroll
    for (int i = 0; i < 16; ++i) {
      int r = i * 4 + rr;
      tile[r][c] = W_in[(size_t)(k0 + r) * 1024 + n0 + c];
    }
    __syncthreads();
#pragma unroll
    for (int i = 0; i < 16; ++i) {
      int r = i * 4 + rr;
      BTin[(size_t)(n0 + r) * 2048 + k0 + c] = f2h(tile[c][r]);
    }
  } else if (bid < 3584) {     // ---- convert [x|h] -> A1 f16
    const int id = bid - 1536;
    int c = id * 256 + t;      // 524288 chunks of 4 floats... (2048 blocks x 256)
    for (; c < 2097152; c += 2048 * 256) {
      int m = c >> 9, kc = (c & 511) << 2;
      const float* src = (kc < 1024) ? (x_t + (size_t)m * 1024 + kc)
                                     : (h_prev + (size_t)m * 1024 + (kc - 1024));
      floatx4 v = *reinterpret_cast<const floatx4*>(src);
      half4 h = {f2h(v[0]), f2h(v[1]), f2h(v[2]), f2h(v[3])};
      *reinterpret_cast<half4*>(&A1[(size_t)m * 2048 + kc]) = h;
    }
  } else {                     // ---- Wqs = W_q @ W_sel (+ bias row)
    const int id = bid - 3584;
    const int w = t >> 6, lane = t & 63;
    const int h = id * 4 + w;
    if (h > 1024) return;
    const float* src = (h < 1024) ? (W_q + (size_t)h * 1024) : b_q;
    float acc = 0.f;
    for (int j = 0; j < 1024; j += 4) {
      floatx4 v = *reinterpret_cast<const floatx4*>(&src[j]);
      acc += v[0] * W_sel[(j + 0) * 64 + lane];
      acc += v[1] * W_sel[(j + 1) * 64 + lane];
      acc += v[2] * W_sel[(j + 2) * 64 + lane];
      acc += v[3] * W_sel[(j + 3) * 64 + lane];
    }
    if (h == 1024) acc += b_sel[lane];
    Wqs[(size_t)h * 64 + lane] = acc;
  }
}

// -------- K2h: A2[:, :1024] = f16(tanh(A1 @ W_in + b_in)), fp16 MFMA --------
// BM=128, BN=64, BK=32, K=2048 -> 64 steps. R12/R14 config (measured floor ~42us).
__global__ __launch_bounds__(256) void k_gemm1h(const _Float16* __restrict__ A1,
                                                const _Float16* __restrict__ BTin,
                                                const float* __restrict__ b_in,
                                                _Float16* __restrict__ A2) {
  __shared__ __align__(16) _Float16 As[4 * 4096];  // [buf][128*32] = 32KB
  __shared__ __align__(16) _Float16 Bs[4 * 2048];  // [buf][64*32]  = 16KB
  const int t = threadIdx.x;
  const int lane = t & 63, w = t >> 6;
  const int wm = w >> 1, wn = w & 1;
  const int m0 = blockIdx.x * 128, n0 = blockIdx.y * 64;
  const int lr = lane & 15, lk = lane >> 4;
  floatx4 acc[4][2];
  floatx4 zero = {0.f, 0.f, 0.f, 0.f};
#pragma unroll
  for (int mi = 0; mi < 4; ++mi)
#pragma unroll
    for (int ni = 0; ni < 2; ++ni) acc[mi][ni] = zero;

  auto stage = [&](int p, int kt) {   // 3 GLL per thread
    const int k0 = kt * 32;
#pragma unroll
    for (int j = 0; j < 2; ++j) {
      int cc = j * 256 + t;
      int row = cc >> 2, sl = cc & 3;
      int sg = sl ^ ((row >> 1) & 3);
      size_t ga = (size_t)(m0 + row) * 2048 + k0 + sg * 8;
      GLL(A1 + ga, &As[p * 4096 + cc * 8]);
    }
    {
      int cc = t;
      int row = cc >> 2, sl = cc & 3;
      int sg = sl ^ ((row >> 1) & 3);
      size_t gb = (size_t)(n0 + row) * 2048 + k0 + sg * 8;
      GLL(BTin + gb, &Bs[p * 2048 + cc * 8]);
    }
  };
  auto compute = [&](int p) {
    half8 af[4], bf[2];
#pragma unroll
    for (int mi = 0; mi < 4; ++mi) {
      int row = wm * 64 + mi * 16 + lr;
      int sl = lk ^ ((row >> 1) & 3);
      af[mi] = *reinterpret_cast<const half8*>(&As[p * 4096 + row * 32 + sl * 8]);
    }
#pragma unroll
    for (int ni = 0; ni < 2; ++ni) {
      int row = wn * 32 + ni * 16 + lr;
      int sl = lk ^ ((row >> 1) & 3);
      bf[ni] = *reinterpret_cast<const half8*>(&Bs[p * 2048 + row * 32 + sl * 8]);
    }
#pragma unroll
    for (int mi = 0; mi < 4; ++mi)
#pragma unroll
      for (int ni = 0; ni < 2; ++ni)
        acc[mi][ni] = __builtin_amdgcn_mfma_f32_16x16x32_f16(af[mi], bf[ni], acc[mi][ni], 0, 0, 0);
  };

  stage(0, 0);
  stage(1, 1);
  stage(2, 2);
  for (int kt = 0; kt < 64; ++kt) {
    __builtin_amdgcn_sched_barrier(0);
    if (kt < 62) {
      asm volatile("s_waitcnt vmcnt(6)" ::: "memory");
    } else if (kt == 62) {
      asm volatile("s_waitcnt vmcnt(3)" ::: "memory");
    } else {
      asm volatile("s_waitcnt vmcnt(0)" ::: "memory");
    }
    __builtin_amdgcn_s_barrier();
    __builtin_amdgcn_sched_barrier(0);
    if (kt + 3 < 64) stage((kt + 3) & 3, kt + 3);
    compute(kt & 3);
  }

#pragma unroll
  for (int mi = 0; mi < 4; ++mi) {
#pragma unroll
    for (int ni = 0; ni < 2; ++ni) {
      int gn = n0 + wn * 32 + ni * 16 + lr;
      float bias = b_in[gn];
      int gmb = m0 + wm * 64 + mi * 16 + lk * 4;
#pragma unroll
      for (int j = 0; j < 4; ++j) {
        int gm = gmb + j;
        A2[(size_t)gm * 2048 + gn] = f2h(tanhf(acc[mi][ni][j] + bias));
      }
    }
  }
}

// ---------------- K2f: fp32 fallback GEMM1 (used when ws too small) ----------------
__global__ __launch_bounds__(256) void k_gemm1(const float* __restrict__ x_t, const float* __restrict__ h_prev,
                                               const float* __restrict__ W_in, const float* __restrict__ b_in,
                                               _Float16* __restrict__ A2) {
  __shared__ float As[16 * 128];
  __shared__ float Bs[16 * 64];
  const int t = threadIdx.x;
  const int m0 = blockIdx.x * 128, n0 = blockIdx.y * 64;
  const int ty = t >> 4, tx = t & 15;
  float acc[8][4];
#pragma unroll
  for (int i = 0; i < 8; ++i)
#pragma unroll
    for (int j = 0; j < 4; ++j) acc[i][j] = 0.f;
  for (int kt = 0; kt < 128; ++kt) {
    const int k0 = kt * 16;
    __syncthreads();
#pragma unroll
    for (int u = 0; u < 2; ++u) {
      int cc = t + u * 256;
      int row = cc >> 2, col4 = (cc & 3) << 2;
      int gk = k0 + col4;
      const float* src = (gk < 1024) ? (x_t + (size_t)(m0 + row) * 1024 + gk)
                                     : (h_prev + (size_t)(m0 + row) * 1024 + (gk - 1024));
      floatx4 v = *reinterpret_cast<const floatx4*>(src);
      As[(col4 + 0) * 128 + row] = v[0];
      As[(col4 + 1) * 128 + row] = v[1];
      As[(col4 + 2) * 128 + row] = v[2];
      As[(col4 + 3) * 128 + row] = v[3];
    }
    {
      int kr = t >> 4, c4 = (t & 15) << 2;
      *reinterpret_cast<floatx4*>(&Bs[kr * 64 + c4]) =
          *reinterpret_cast<const floatx4*>(&W_in[(size_t)(k0 + kr) * 1024 + n0 + c4]);
    }
    __syncthreads();
#pragma unroll
    for (int kk = 0; kk < 16; ++kk) {
      floatx4 a0 = *reinterpret_cast<const floatx4*>(&As[kk * 128 + ty * 8]);
      floatx4 a1 = *reinterpret_cast<const floatx4*>(&As[kk * 128 + ty * 8 + 4]);
      floatx4 b = *reinterpret_cast<const floatx4*>(&Bs[kk * 64 + tx * 4]);
#pragma unroll
      for (int j = 0; j < 4; ++j) {
        acc[0][j] += a0[0] * b[j]; acc[1][j] += a0[1] * b[j];
        acc[2][j] += a0[2] * b[j]; acc[3][j] += a0[3] * b[j];
        acc[4][j] += a1[0] * b[j]; acc[5][j] += a1[1] * b[j];
        acc[6][j] += a1[2] * b[j]; acc[7][j] += a1[3] * b[j];
      }
    }
  }
  const int nbase = n0 + tx * 4;
  floatx4 bias = *reinterpret_cast<const floatx4*>(&b_in[nbase]);
#pragma unroll
  for (int i = 0; i < 8; ++i) {
    int gm = m0 + ty * 8 + i;
    half4 pk;
#pragma unroll
    for (int j = 0; j < 4; ++j) pk[j] = f2h(tanhf(acc[i][j] + bias[j]));
    *reinterpret_cast<half4*>(&A2[(size_t)gm * 2048 + nbase]) = pk;
  }
}

// ------- K4: logits = h(f16) @ Wqs + bqs; argmax; flag gap<TAU. 16 rows/block -------
__global__ __launch_bounds__(256) void k_argmax(const _Float16* __restrict__ A2, const float* __restrict__ Wqs,
                                                int* __restrict__ idx, int* __restrict__ counter,
                                                int* __restrict__ list, float tau) {
  __shared__ float Ahs[64 * 17];  // [k][r] stride 17
  __shared__ float Wt[64 * 64];   // [k][s]
  const int t = threadIdx.x;
  const int r0 = blockIdx.x * 16;
  const int w = t >> 6, lane = t & 63;
  float acc[4] = {0.f, 0.f, 0.f, 0.f};

  for (int kt = 0; kt < 16; ++kt) {
    const int k0 = kt * 64;
    __syncthreads();
    if (t < 128) {
      int r = t >> 3, k8 = (t & 7) * 8;
      half8 v = *reinterpret_cast<const half8*>(&A2[(size_t)(r0 + r) * 2048 + k0 + k8]);
#pragma unroll
      for (int j = 0; j < 8; ++j) Ahs[(k8 + j) * 17 + r] = (float)v[j];
    }
#pragma unroll
    for (int u = 0; u < 4; ++u) {
      int cc = t + u * 256;
      int kr = cc >> 4, c4 = (cc & 15) << 2;
      *reinterpret_cast<floatx4*>(&Wt[kr * 64 + c4]) =
          *reinterpret_cast<const floatx4*>(&Wqs[(size_t)(k0 + kr) * 64 + c4]);
    }
    __syncthreads();
#pragma unroll
    for (int k = 0; k < 64; ++k) {
      float wv = Wt[k * 64 + lane];
      const float* ar = &Ahs[k * 17 + w * 4];
      acc[0] += ar[0] * wv;
      acc[1] += ar[1] * wv;
      acc[2] += ar[2] * wv;
      acc[3] += ar[3] * wv;
    }
  }
  const float bqs = Wqs[1024 * 64 + lane];
#pragma unroll
  for (int i = 0; i < 4; ++i) {
    float v1 = acc[i] + bqs;
    int i1 = lane;
    float v2 = -__builtin_inff();
#pragma unroll
    for (int off = 32; off >= 1; off >>= 1) {
      float ov1 = __shfl_xor(v1, off);
      int oi1 = __shfl_xor(i1, off);
      float ov2 = __shfl_xor(v2, off);
      if (ov1 > v1 || (ov1 == v1 && oi1 < i1)) {
        v2 = fmaxf(v1, ov2); v1 = ov1; i1 = oi1;
      } else {
        v2 = fmaxf(v2, ov1);
      }
    }
    if (lane == 0) {
      int row = r0 + w * 4 + i;
      idx[row] = i1;
      if (v1 - v2 < tau) {
        int pos = atomicAdd(counter, 1);
        if (pos < FIX_CAP) list[pos] = row;
      }
    }
  }
}

// ------- K4b: batched exact fp32 z, LDS-staged W -------
__global__ __launch_bounds__(256) void k_fixA3(const float* __restrict__ x_t, const float* __restrict__ h_prev,
                                               const float* __restrict__ W_in, const int* __restrict__ counter,
                                               const int* __restrict__ list, float* __restrict__ scratch) {
  __shared__ float Ws[256 * 64];   // [k][col] 64KB
  __shared__ float xr[8][260];
  const int t = threadIdx.x;
  const int cnt = min(counter[0], FIX_CAP);
  const int nbatch = (cnt + 7) >> 3;
  const int col = t & 63;
  const int rp = t >> 6;
  const int gcol = blockIdx.x * 64 + col;
  for (int mb = blockIdx.y; mb < nbatch; mb += gridDim.y) {
    const int rbase = mb * 8;
    float a0[4] = {0.f, 0.f, 0.f, 0.f};
    float a1[4] = {0.f, 0.f, 0.f, 0.f};
    for (int kc = 0; kc < 8; ++kc) {
      __syncthreads();
      {
        int r = t >> 5, kl = (t & 31) * 8;
        int e = rbase + r;
        int row = list[e < cnt ? e : 0];
        int kg = kc * 256 + kl;
        const float* src = (kg < 1024) ? (x_t + (size_t)row * 1024 + kg)
                                       : (h_prev + (size_t)row * 1024 + (kg - 1024));
        floatx4 v0 = *reinterpret_cast<const floatx4*>(src);
        floatx4 v1 = *reinterpret_cast<const floatx4*>(src + 4);
        *reinterpret_cast<floatx4*>(&xr[r][kl]) = v0;
        *reinterpret_cast<floatx4*>(&xr[r][kl + 4]) = v1;
      }
      {
        const float* Wb = W_in + (size_t)(kc * 256) * 1024 + blockIdx.x * 64;
#pragma unroll
        for (int i = 0; i < 16; ++i) {
          int f = t + 256 * i;
          int k = f >> 4, c4 = (f & 15) << 2;
          floatx4 v = *reinterpret_cast<const floatx4*>(Wb + (size_t)k * 1024 + c4);
          *reinterpret_cast<floatx4*>(&Ws[k * 64 + c4]) = v;
        }
      }
      __syncthreads();
      const floatx4* x0v = reinterpret_cast<const floatx4*>(xr[rp * 2]);
      const floatx4* x1v = reinterpret_cast<const floatx4*>(xr[rp * 2 + 1]);
      for (int k4 = 0; k4 < 64; ++k4) {
        floatx4 xv0 = x0v[k4];
        floatx4 xv1 = x1v[k4];
        int kb = k4 * 4;
        float w0 = Ws[(kb + 0) * 64 + col];
        float w1 = Ws[(kb + 1) * 64 + col];
        float w2 = Ws[(kb + 2) * 64 + col];
        float w3 = Ws[(kb + 3) * 64 + col];
        a0[0] += xv0[0] * w0; a1[0] += xv1[0] * w0;
        a0[1] += xv0[1] * w1; a1[1] += xv1[1] * w1;
        a0[2] += xv0[2] * w2; a1[2] += xv1[2] * w2;
        a0[3] += xv0[3] * w3; a1[3] += xv1[3] * w3;
      }
    }
    float z0 = (a0[0] + a0[1]) + (a0[2] + a0[3]);
    float z1 = (a1[0] + a1[1]) + (a1[2] + a1[3]);
    int e0 = rbase + rp * 2, e1 = e0 + 1;
    if (e0 < cnt) scratch[(size_t)e0 * 1024 + gcol] = z0;
    if (e1 < cnt) scratch[(size_t)e1 * 1024 + gcol] = z1;
    __syncthreads();
  }
}

// ------- K4c: block-per-row: h=tanh(z+b) -> logits (ILP-8) -> argmax -> idx -------
__global__ __launch_bounds__(256) void k_fixB(const float* __restrict__ scratch, const float* __restrict__ b_in,
                                              const float* __restrict__ Wqs, const int* __restrict__ counter,
                                              const int* __restrict__ list, int* __restrict__ idx) {
  __shared__ float hrow[1024];
  __shared__ float partial[4 * 64];
  __shared__ float lg[64];
  const int t = threadIdx.x;
  const int cnt = min(counter[0], FIX_CAP);
  const int e = blockIdx.x;
  if (e >= cnt) return;
  const int r = list[e];
  const int n4 = t * 4;
  floatx4 b4 = *reinterpret_cast<const floatx4*>(&b_in[n4]);
  floatx4 z4 = *reinterpret_cast<const floatx4*>(&scratch[(size_t)e * 1024 + n4]);
  hrow[n4 + 0] = tanhf(z4[0] + b4[0]);
  hrow[n4 + 1] = tanhf(z4[1] + b4[1]);
  hrow[n4 + 2] = tanhf(z4[2] + b4[2]);
  hrow[n4 + 3] = tanhf(z4[3] + b4[3]);
  __syncthreads();
  const int s = t & 63, part = t >> 6;
  const int hb0 = part * 256;
  const float* Wp = Wqs + (size_t)hb0 * 64 + s;
  float p0 = 0.f, p1 = 0.f, p2 = 0.f, p3 = 0.f, p4 = 0.f, p5 = 0.f, p6 = 0.f, p7 = 0.f;
  for (int h8 = 0; h8 < 256; h8 += 8) {
    float w0 = Wp[(size_t)(h8 + 0) * 64];
    float w1 = Wp[(size_t)(h8 + 1) * 64];
    float w2 = Wp[(size_t)(h8 + 2) * 64];
    float w3 = Wp[(size_t)(h8 + 3) * 64];
    float w4 = Wp[(size_t)(h8 + 4) * 64];
    float w5 = Wp[(size_t)(h8 + 5) * 64];
    float w6 = Wp[(size_t)(h8 + 6) * 64];
    float w7 = Wp[(size_t)(h8 + 7) * 64];
    const int hb = hb0 + h8;
    p0 += hrow[hb + 0] * w0;
    p1 += hrow[hb + 1] * w1;
    p2 += hrow[hb + 2] * w2;
    p3 += hrow[hb + 3] * w3;
    p4 += hrow[hb + 4] * w4;
    p5 += hrow[hb + 5] * w5;
    p6 += hrow[hb + 6] * w6;
    p7 += hrow[hb + 7] * w7;
  }
  partial[part * 64 + s] = ((p0 + p1) + (p2 + p3)) + ((p4 + p5) + (p6 + p7));
  __syncthreads();
  if (t < 64) lg[t] = partial[t] + partial[64 + t] + partial[128 + t] + partial[192 + t] + Wqs[1024 * 64 + t];
  __syncthreads();
  if (t == 0) {
    float bv = lg[0]; int bi = 0;
    for (int ss = 1; ss < 64; ++ss) {
      if (lg[ss] > bv) { bv = lg[ss]; bi = ss; }
    }
    idx[r] = bi;
  }
}

// ---------------- K5: mixture: angles -> cos -> m_t (block per row, h from A2 f16) --------
__global__ __launch_bounds__(256) void k_mix(const _Float16* __restrict__ A2h, const int* __restrict__ idx,
                                             const float* __restrict__ Wm_enc, const float* __restrict__ theta,
                                             const float* __restrict__ Wm_dec, const float* __restrict__ b_m,
                                             _Float16* __restrict__ A2) {
  __shared__ float hrow[1024];
  __shared__ float partial[256];
  __shared__ float expz[16];
  const int b = blockIdx.x, t = threadIdx.x;
  const int s = idx[b];
  {
    half4 v = *reinterpret_cast<const half4*>(&A2h[(size_t)b * 2048 + t * 4]);
    hrow[t * 4 + 0] = (float)v[0];
    hrow[t * 4 + 1] = (float)v[1];
    hrow[t * 4 + 2] = (float)v[2];
    hrow[t * 4 + 3] = (float)v[3];
  }
  __syncthreads();
  const int q = t & 15, g = t >> 4;
  const float* We = Wm_enc + (size_t)s * 16384;
  float p = 0.f;
#pragma unroll 8
  for (int j = 0; j < 64; ++j) {
    int h = g + j * 16;
    p += hrow[h] * We[h * 16 + q];
  }
  partial[t] = p;
  __syncthreads();
  if (t < 16) {
    float a = 0.f;
#pragma unroll
    for (int g2 = 0; g2 < 16; ++g2) a += partial[g2 * 16 + t];
    a += theta[s * 16 + t];
    expz[t] = cosf(a);
  }
  __syncthreads();
  const float* Wd = Wm_dec + (size_t)s * 16384;
  float e[16];
#pragma unroll
  for (int qq = 0; qq < 16; ++qq) e[qq] = expz[qq];
#pragma unroll
  for (int r = 0; r < 4; ++r) {
    int h = r * 256 + t;
    float v = b_m[h];
#pragma unroll
    for (int qq = 0; qq < 16; ++qq) v += e[qq] * Wd[qq * 1024 + h];
    A2[(size_t)b * 2048 + 1024 + h] = f2h(tanhf(v));
  }
}

// ---------------- K6: goh = A2 @ BT^T + b_og -> tanh/split epilogue, fp16 MFMA ----------------
// 128x128 tile, BK=32, R12/R14 config (measured floor ~65us).
__global__ __launch_bounds__(256) void k_gemm4h(const _Float16* __restrict__ A2,
                                                const _Float16* __restrict__ BT,
                                                const float* __restrict__ b_og, float* __restrict__ out) {
  __shared__ __align__(16) _Float16 As[4 * 4096];  // 32KB
  __shared__ __align__(16) _Float16 Bs[4 * 4096];  // 32KB
  const int t = threadIdx.x;
  const int lane = t & 63, w = t >> 6;
  const int wm = w >> 1, wn = w & 1;
  const int m0 = blockIdx.x * 128, n0 = blockIdx.y * 128;
  const int lr = lane & 15, lk = lane >> 4;
  floatx4 acc[4][4];
  floatx4 zero = {0.f, 0.f, 0.f, 0.f};
#pragma unroll
  for (int mi = 0; mi < 4; ++mi)
#pragma unroll
    for (int ni = 0; ni < 4; ++ni) acc[mi][ni] = zero;

  auto stage = [&](int p, int kt) {   // 4 GLL per thread
    const int k0 = kt * 32;
#pragma unroll
    for (int j = 0; j < 2; ++j) {
      int cc = j * 256 + t;
      int row = cc >> 2, sl = cc & 3;
      int sg = sl ^ ((row >> 1) & 3);
      size_t ga = (size_t)(m0 + row) * 2048 + k0 + sg * 8;
      size_t gb = (size_t)(n0 + row) * 2048 + k0 + sg * 8;
      GLL(A2 + ga, &As[p * 4096 + cc * 8]);
      GLL(BT + gb, &Bs[p * 4096 + cc * 8]);
    }
  };
  auto compute = [&](int p) {
    half8 af[4], bf[4];
#pragma unroll
    for (int mi = 0; mi < 4; ++mi) {
      int row = wm * 64 + mi * 16 + lr;
      int sl = lk ^ ((row >> 1) & 3);
      af[mi] = *reinterpret_cast<const half8*>(&As[p * 4096 + row * 32 + sl * 8]);
    }
#pragma unroll
    for (int ni = 0; ni < 4; ++ni) {
      int row = wn * 64 + ni * 16 + lr;
      int sl = lk ^ ((row >> 1) & 3);
      bf[ni] = *reinterpret_cast<const half8*>(&Bs[p * 4096 + row * 32 + sl * 8]);
    }
#pragma unroll
    for (int mi = 0; mi < 4; ++mi)
#pragma unroll
      for (int ni = 0; ni < 4; ++ni)
        acc[mi][ni] = __builtin_amdgcn_mfma_f32_16x16x32_f16(af[mi], bf[ni], acc[mi][ni], 0, 0, 0);
  };

  stage(0, 0);
  stage(1, 1);
  stage(2, 2);
  for (int kt = 0; kt < 64; ++kt) {
    __builtin_amdgcn_sched_barrier(0);
    if (kt < 62) {
      asm volatile("s_waitcnt vmcnt(8)" ::: "memory");
    } else if (kt == 62) {
      asm volatile("s_waitcnt vmcnt(4)" ::: "memory");
    } else {
      asm volatile("s_waitcnt vmcnt(0)" ::: "memory");
    }
    __builtin_amdgcn_s_barrier();
    __builtin_amdgcn_sched_barrier(0);
    if (kt + 3 < 64) stage((kt + 3) & 3, kt + 3);
    compute(kt & 3);
  }

#pragma unroll
  for (int mi = 0; mi < 4; ++mi) {
#pragma unroll
    for (int ni = 0; ni < 4; ++ni) {
      int gn = n0 + wn * 64 + ni * 16 + lr;
      float bias = b_og[gn];
      int gmb = m0 + wm * 64 + mi * 16 + lk * 4;
#pragma unroll
      for (int j = 0; j < 4; ++j) {
        int gm = gmb + j;
        float v = acc[mi][ni][j] + bias;
        if (gn < 1024) {
          out[OUT_H_OFF + (size_t)gm * 1024 + gn] = tanhf(v);  // h_next
        } else {
          out[(size_t)gm * 1024 + (gn - 1024)] = v;            // y_t
        }
      }
    }
  }
}

extern "C" void kernel_launch(void* const* d_in, const int* in_sizes, int n_in,
                              void* d_out, int out_size, void* d_ws, size_t ws_size,
                              hipStream_t stream) {
  (void)in_sizes; (void)n_in; (void)out_size;
  const float* x_t    = (const float*)d_in[0];
  const float* h_prev = (const float*)d_in[1];
  const float* W_in   = (const float*)d_in[2];
  const float* b_in   = (const float*)d_in[3];
  const float* W_q    = (const float*)d_in[4];
  const float* b_q    = (const float*)d_in[5];
  const float* W_sel  = (const float*)d_in[6];
  const float* b_sel  = (const float*)d_in[7];
  const float* Wm_enc = (const float*)d_in[8];
  const float* theta  = (const float*)d_in[9];
  const float* Wm_dec = (const float*)d_in[10];
  const float* b_m    = (const float*)d_in[11];
  const float* W_og   = (const float*)d_in[12];
  const float* b_og   = (const float*)d_in[13];
  float* out = (float*)d_out;

  char* ws = (char*)d_ws;
  _Float16* A2          = (_Float16*)(ws + ((size_t)16 << 20));
  _Float16* BT          = (_Float16*)(ws + ((size_t)32 << 20));
  float* Wqs            = (float*)(ws + ((size_t)40 << 20));
  int* idx              = (int*)(ws + ((size_t)41 << 20));
  int* counter          = (int*)(ws + ((size_t)41 << 20) + 16384);
  int* list             = (int*)(ws + ((size_t)41 << 20) + 16384 + 64);
  _Float16* A1          = (_Float16*)(ws + ((size_t)42 << 20));
  _Float16* BTin        = (_Float16*)(ws + ((size_t)58 << 20));
  float* fix_scratch    = (float*)(ws + ((size_t)62 << 20));

  const bool use_mfma = ws_size >= ((size_t)82 << 20);

  hipMemsetAsync(counter, 0, 4, stream);
  hipLaunchKernelGGL(k_prep, dim3(3841), dim3(256), 0, stream,
                     W_og, BT, W_in, BTin, x_t, h_prev, A1, W_q, b_q, W_sel, b_sel, Wqs);

  if (use_mfma) {
    hipLaunchKernelGGL(k_gemm1h, dim3(32, 16), dim3(256), 0, stream,
                       A1, BTin, b_in, A2);
    hipLaunchKernelGGL(k_argmax, dim3(256), dim3(256), 0, stream, A2, Wqs, idx, counter, list, TAU);
    hipLaunchKernelGGL(k_fixA3, dim3(16, 32), dim3(256), 0, stream,
                       x_t, h_prev, W_in, counter, list, fix_scratch);
    hipLaunchKernelGGL(k_fixB, dim3(FIX_CAP), dim3(256), 0, stream,
                       fix_scratch, b_in, Wqs, counter, list, idx);
  } else {
    hipLaunchKernelGGL(k_gemm1, dim3(32, 16), dim3(256), 0, stream, x_t, h_prev, W_in, b_in, A2);
    hipLaunchKernelGGL(k_argmax, dim3(256), dim3(256), 0, stream, A2, Wqs, idx, counter, list, 0.0f);
  }

  hipLaunchKernelGGL(k_mix, dim3(4096), dim3(256), 0, stream, A2, idx, Wm_enc, theta, Wm_dec, b_m, A2);
  hipLaunchKernelGGL(k_gemm4h, dim3(32, 16), dim3(256), 0, stream, A2, BT, b_og, out);
}

// Round 17
// 254.075 us; speedup vs baseline: 1.2420x; 1.0861x over previous
//
#include <hip/hip_runtime.h>
#include <math.h>

// Shapes: B=4096, IN=1024, H=1024, S=64, Q=16, OUT=1024
// ws layout:
//   [16,32MB)   A2 f16 [4096][2048]  (cols 0-1023 = h_int f16, 1024-2047 = m_t)
//   [32,40MB)   BT f16 [2048][2048]  (= W_og^T)
//   [40,41MB)   Wqs f32 [1025][64]
//   [41MB)      idx int[4096]; counter; list
//   [42,58MB)   A1 f16 [4096][2048]  ([x|h] converted)
//   [58,62MB)   BTin f16 [1024][2048] (W_in^T)
//   [62,78MB)   fix_scratch f32 [FIX_CAP][1024]

typedef __attribute__((ext_vector_type(4))) float floatx4;
typedef __attribute__((ext_vector_type(8))) _Float16 half8;
typedef __attribute__((ext_vector_type(4))) _Float16 half4;

#define OUT_H_OFF 4194304
#define TAU 4e-3f
#define FIX_CAP 512

#define AS1 __attribute__((address_space(1)))
#define AS3 __attribute__((address_space(3)))
#define GLL(gptr, lptr) __builtin_amdgcn_global_load_lds((const AS1 void*)(gptr), (AS3 void*)(lptr), 16, 0, 0)

__device__ __forceinline__ _Float16 f2h(float f) { return (_Float16)f; }  // v_cvt_f16_f32, RNE

// ---------------- K1: BT[n][k] = f16(W_og[k][n]), 2048x2048 ----------------
__global__ __launch_bounds__(256) void k_transpose(const float* __restrict__ W,
                                                   _Float16* __restrict__ BT) {
  __shared__ float tile[64][65];
  const int k0 = blockIdx.x * 64, n0 = blockIdx.y * 64;
  const int t = threadIdx.x, c = t & 63, rr = t >> 6;
#pragma unroll
  for (int i = 0; i < 16; ++i) {
    int r = i * 4 + rr;
    tile[r][c] = W[(size_t)(k0 + r) * 2048 + n0 + c];
  }
  __syncthreads();
#pragma unroll
  for (int i = 0; i < 16; ++i) {
    int r = i * 4 + rr;  // n-local
    BT[(size_t)(n0 + r) * 2048 + k0 + c] = f2h(tile[c][r]);
  }
}

// ---------------- K1b: convert A = [x|h] -> A1 f16 [4096][2048] --------
__global__ __launch_bounds__(256) void k_convA(const float* __restrict__ x_t, const float* __restrict__ h_prev,
                                               _Float16* __restrict__ A1) {
  const int stride = gridDim.x * blockDim.x;
  for (int c = blockIdx.x * blockDim.x + threadIdx.x; c < 2097152; c += stride) {
    int m = c >> 9, kc = (c & 511) << 2;
    const float* src = (kc < 1024) ? (x_t + (size_t)m * 1024 + kc)
                                   : (h_prev + (size_t)m * 1024 + (kc - 1024));
    floatx4 v = *reinterpret_cast<const floatx4*>(src);
    half4 h = {f2h(v[0]), f2h(v[1]), f2h(v[2]), f2h(v[3])};
    *reinterpret_cast<half4*>(&A1[(size_t)m * 2048 + kc]) = h;
  }
}

// ------- K1c: convert+transpose W_in [2048][1024] -> BTin f16 [1024][2048] -------
__global__ __launch_bounds__(256) void k_convB(const float* __restrict__ W_in,
                                               _Float16* __restrict__ BTin) {
  __shared__ float tile[64][65];
  const int k0 = blockIdx.x * 64, n0 = blockIdx.y * 64;
  const int t = threadIdx.x, c = t & 63, rr = t >> 6;
#pragma unroll
  for (int i = 0; i < 16; ++i) {
    int r = i * 4 + rr;
    tile[r][c] = W_in[(size_t)(k0 + r) * 1024 + n0 + c];
  }
  __syncthreads();
#pragma unroll
  for (int i = 0; i < 16; ++i) {
    int r = i * 4 + rr;  // n-local
    BTin[(size_t)(n0 + r) * 2048 + k0 + c] = f2h(tile[c][r]);
  }
}

// -------- K2h: A2[:, :1024] = f16(tanh(A1 @ W_in + b_in)), fp16 MFMA --------
// BM=128, BN=64, BK=32, K=2048 -> 64 steps. R12/R14 config (measured floor).
__global__ __launch_bounds__(256) void k_gemm1h(const _Float16* __restrict__ A1,
                                                const _Float16* __restrict__ BTin,
                                                const float* __restrict__ b_in,
                                                _Float16* __restrict__ A2) {
  __shared__ __align__(16) _Float16 As[4 * 4096];  // [buf][128*32] = 32KB
  __shared__ __align__(16) _Float16 Bs[4 * 2048];  // [buf][64*32]  = 16KB
  const int t = threadIdx.x;
  const int lane = t & 63, w = t >> 6;
  const int wm = w >> 1, wn = w & 1;
  const int m0 = blockIdx.x * 128, n0 = blockIdx.y * 64;
  const int lr = lane & 15, lk = lane >> 4;
  floatx4 acc[4][2];
  floatx4 zero = {0.f, 0.f, 0.f, 0.f};
#pragma unroll
  for (int mi = 0; mi < 4; ++mi)
#pragma unroll
    for (int ni = 0; ni < 2; ++ni) acc[mi][ni] = zero;

  auto stage = [&](int p, int kt) {   // 3 GLL per thread
    const int k0 = kt * 32;
#pragma unroll
    for (int j = 0; j < 2; ++j) {
      int cc = j * 256 + t;
      int row = cc >> 2, sl = cc & 3;
      int sg = sl ^ ((row >> 1) & 3);
      size_t ga = (size_t)(m0 + row) * 2048 + k0 + sg * 8;
      GLL(A1 + ga, &As[p * 4096 + cc * 8]);
    }
    {
      int cc = t;
      int row = cc >> 2, sl = cc & 3;
      int sg = sl ^ ((row >> 1) & 3);
      size_t gb = (size_t)(n0 + row) * 2048 + k0 + sg * 8;
      GLL(BTin + gb, &Bs[p * 2048 + cc * 8]);
    }
  };
  auto compute = [&](int p) {
    half8 af[4], bf[2];
#pragma unroll
    for (int mi = 0; mi < 4; ++mi) {
      int row = wm * 64 + mi * 16 + lr;
      int sl = lk ^ ((row >> 1) & 3);
      af[mi] = *reinterpret_cast<const half8*>(&As[p * 4096 + row * 32 + sl * 8]);
    }
#pragma unroll
    for (int ni = 0; ni < 2; ++ni) {
      int row = wn * 32 + ni * 16 + lr;
      int sl = lk ^ ((row >> 1) & 3);
      bf[ni] = *reinterpret_cast<const half8*>(&Bs[p * 2048 + row * 32 + sl * 8]);
    }
#pragma unroll
    for (int mi = 0; mi < 4; ++mi)
#pragma unroll
      for (int ni = 0; ni < 2; ++ni)
        acc[mi][ni] = __builtin_amdgcn_mfma_f32_16x16x32_f16(af[mi], bf[ni], acc[mi][ni], 0, 0, 0);
  };

  stage(0, 0);
  stage(1, 1);
  stage(2, 2);
  for (int kt = 0; kt < 64; ++kt) {
    __builtin_amdgcn_sched_barrier(0);
    if (kt < 62) {
      asm volatile("s_waitcnt vmcnt(6)" ::: "memory");
    } else if (kt == 62) {
      asm volatile("s_waitcnt vmcnt(3)" ::: "memory");
    } else {
      asm volatile("s_waitcnt vmcnt(0)" ::: "memory");
    }
    __builtin_amdgcn_s_barrier();
    __builtin_amdgcn_sched_barrier(0);
    if (kt + 3 < 64) stage((kt + 3) & 3, kt + 3);
    compute(kt & 3);
  }

#pragma unroll
  for (int mi = 0; mi < 4; ++mi) {
#pragma unroll
    for (int ni = 0; ni < 2; ++ni) {
      int gn = n0 + wn * 32 + ni * 16 + lr;
      float bias = b_in[gn];
      int gmb = m0 + wm * 64 + mi * 16 + lk * 4;
#pragma unroll
      for (int j = 0; j < 4; ++j) {
        int gm = gmb + j;
        A2[(size_t)gm * 2048 + gn] = f2h(tanhf(acc[mi][ni][j] + bias));
      }
    }
  }
}

// ---------------- K2f: fp32 fallback GEMM1 (used when ws too small) ----------------
__global__ __launch_bounds__(256) void k_gemm1(const float* __restrict__ x_t, const float* __restrict__ h_prev,
                                               const float* __restrict__ W_in, const float* __restrict__ b_in,
                                               _Float16* __restrict__ A2) {
  __shared__ float As[16 * 128];
  __shared__ float Bs[16 * 64];
  const int t = threadIdx.x;
  const int m0 = blockIdx.x * 128, n0 = blockIdx.y * 64;
  const int ty = t >> 4, tx = t & 15;
  float acc[8][4];
#pragma unroll
  for (int i = 0; i < 8; ++i)
#pragma unroll
    for (int j = 0; j < 4; ++j) acc[i][j] = 0.f;
  for (int kt = 0; kt < 128; ++kt) {
    const int k0 = kt * 16;
    __syncthreads();
#pragma unroll
    for (int u = 0; u < 2; ++u) {
      int cc = t + u * 256;
      int row = cc >> 2, col4 = (cc & 3) << 2;
      int gk = k0 + col4;
      const float* src = (gk < 1024) ? (x_t + (size_t)(m0 + row) * 1024 + gk)
                                     : (h_prev + (size_t)(m0 + row) * 1024 + (gk - 1024));
      floatx4 v = *reinterpret_cast<const floatx4*>(src);
      As[(col4 + 0) * 128 + row] = v[0];
      As[(col4 + 1) * 128 + row] = v[1];
      As[(col4 + 2) * 128 + row] = v[2];
      As[(col4 + 3) * 128 + row] = v[3];
    }
    {
      int kr = t >> 4, c4 = (t & 15) << 2;
      *reinterpret_cast<floatx4*>(&Bs[kr * 64 + c4]) =
          *reinterpret_cast<const floatx4*>(&W_in[(size_t)(k0 + kr) * 1024 + n0 + c4]);
    }
    __syncthreads();
#pragma unroll
    for (int kk = 0; kk < 16; ++kk) {
      floatx4 a0 = *reinterpret_cast<const floatx4*>(&As[kk * 128 + ty * 8]);
      floatx4 a1 = *reinterpret_cast<const floatx4*>(&As[kk * 128 + ty * 8 + 4]);
      floatx4 b = *reinterpret_cast<const floatx4*>(&Bs[kk * 64 + tx * 4]);
#pragma unroll
      for (int j = 0; j < 4; ++j) {
        acc[0][j] += a0[0] * b[j]; acc[1][j] += a0[1] * b[j];
        acc[2][j] += a0[2] * b[j]; acc[3][j] += a0[3] * b[j];
        acc[4][j] += a1[0] * b[j]; acc[5][j] += a1[1] * b[j];
        acc[6][j] += a1[2] * b[j]; acc[7][j] += a1[3] * b[j];
      }
    }
  }
  const int nbase = n0 + tx * 4;
  floatx4 bias = *reinterpret_cast<const floatx4*>(&b_in[nbase]);
#pragma unroll
  for (int i = 0; i < 8; ++i) {
    int gm = m0 + ty * 8 + i;
    half4 pk;
#pragma unroll
    for (int j = 0; j < 4; ++j) pk[j] = f2h(tanhf(acc[i][j] + bias[j]));
    *reinterpret_cast<half4*>(&A2[(size_t)gm * 2048 + nbase]) = pk;
  }
}

// ---------------- K3: Wqs = W_q @ W_sel (+ fused bias row 1024), ILP-8 ----------------
// 8 independent accumulators + 8 loads in flight break the 1024-long serial fadd
// chain (same restructure that fixed k_fixB in R9: 118us -> ~4us).
__global__ __launch_bounds__(256) void k_wqs(const float* __restrict__ W_q, const float* __restrict__ b_q,
                                             const float* __restrict__ W_sel, const float* __restrict__ b_sel,
                                             float* __restrict__ Wqs) {
  const int t = threadIdx.x;
  const int w = t >> 6, lane = t & 63;
  const int h = blockIdx.x * 4 + w;
  if (h > 1024) return;
  const float* src = (h < 1024) ? (W_q + (size_t)h * 1024) : b_q;
  const float* Wp = W_sel + lane;
  float a0 = 0.f, a1 = 0.f, a2 = 0.f, a3 = 0.f, a4 = 0.f, a5 = 0.f, a6 = 0.f, a7 = 0.f;
  for (int j = 0; j < 1024; j += 8) {
    floatx4 v0 = *reinterpret_cast<const floatx4*>(&src[j]);
    floatx4 v1 = *reinterpret_cast<const floatx4*>(&src[j + 4]);
    float w0 = Wp[(size_t)(j + 0) * 64];
    float w1 = Wp[(size_t)(j + 1) * 64];
    float w2 = Wp[(size_t)(j + 2) * 64];
    float w3 = Wp[(size_t)(j + 3) * 64];
    float w4 = Wp[(size_t)(j + 4) * 64];
    float w5 = Wp[(size_t)(j + 5) * 64];
    float w6 = Wp[(size_t)(j + 6) * 64];
    float w7 = Wp[(size_t)(j + 7) * 64];
    a0 += v0[0] * w0;
    a1 += v0[1] * w1;
    a2 += v0[2] * w2;
    a3 += v0[3] * w3;
    a4 += v1[0] * w4;
    a5 += v1[1] * w5;
    a6 += v1[2] * w6;
    a7 += v1[3] * w7;
  }
  float acc = ((a0 + a1) + (a2 + a3)) + ((a4 + a5) + (a6 + a7));
  if (h == 1024) acc += b_sel[lane];
  Wqs[(size_t)h * 64 + lane] = acc;
}

// ------- K4: logits = h(f16) @ Wqs + bqs; argmax; flag gap<TAU. 16 rows/block -------
__global__ __launch_bounds__(256) void k_argmax(const _Float16* __restrict__ A2, const float* __restrict__ Wqs,
                                                int* __restrict__ idx, int* __restrict__ counter,
                                                int* __restrict__ list, float tau) {
  __shared__ float Ahs[64 * 17];  // [k][r] stride 17
  __shared__ float Wt[64 * 64];   // [k][s]
  const int t = threadIdx.x;
  const int r0 = blockIdx.x * 16;
  const int w = t >> 6, lane = t & 63;
  float acc[4] = {0.f, 0.f, 0.f, 0.f};

  for (int kt = 0; kt < 16; ++kt) {
    const int k0 = kt * 64;
    __syncthreads();
    if (t < 128) {
      int r = t >> 3, k8 = (t & 7) * 8;
      half8 v = *reinterpret_cast<const half8*>(&A2[(size_t)(r0 + r) * 2048 + k0 + k8]);
#pragma unroll
      for (int j = 0; j < 8; ++j) Ahs[(k8 + j) * 17 + r] = (float)v[j];
    }
#pragma unroll
    for (int u = 0; u < 4; ++u) {
      int cc = t + u * 256;
      int kr = cc >> 4, c4 = (cc & 15) << 2;
      *reinterpret_cast<floatx4*>(&Wt[kr * 64 + c4]) =
          *reinterpret_cast<const floatx4*>(&Wqs[(size_t)(k0 + kr) * 64 + c4]);
    }
    __syncthreads();
#pragma unroll
    for (int k = 0; k < 64; ++k) {
      float wv = Wt[k * 64 + lane];
      const float* ar = &Ahs[k * 17 + w * 4];
      acc[0] += ar[0] * wv;
      acc[1] += ar[1] * wv;
      acc[2] += ar[2] * wv;
      acc[3] += ar[3] * wv;
    }
  }
  const float bqs = Wqs[1024 * 64 + lane];
#pragma unroll
  for (int i = 0; i < 4; ++i) {
    float v1 = acc[i] + bqs;
    int i1 = lane;
    float v2 = -__builtin_inff();
#pragma unroll
    for (int off = 32; off >= 1; off >>= 1) {
      float ov1 = __shfl_xor(v1, off);
      int oi1 = __shfl_xor(i1, off);
      float ov2 = __shfl_xor(v2, off);
      if (ov1 > v1 || (ov1 == v1 && oi1 < i1)) {
        v2 = fmaxf(v1, ov2); v1 = ov1; i1 = oi1;
      } else {
        v2 = fmaxf(v2, ov1);
      }
    }
    if (lane == 0) {
      int row = r0 + w * 4 + i;
      idx[row] = i1;
      if (v1 - v2 < tau) {
        int pos = atomicAdd(counter, 1);
        if (pos < FIX_CAP) list[pos] = row;
      }
    }
  }
}

// ------- K4b: batched exact fp32 z, LDS-staged W -------
__global__ __launch_bounds__(256) void k_fixA3(const float* __restrict__ x_t, const float* __restrict__ h_prev,
                                               const float* __restrict__ W_in, const int* __restrict__ counter,
                                               const int* __restrict__ list, float* __restrict__ scratch) {
  __shared__ float Ws[256 * 64];   // [k][col] 64KB
  __shared__ float xr[8][260];
  const int t = threadIdx.x;
  const int cnt = min(counter[0], FIX_CAP);
  const int nbatch = (cnt + 7) >> 3;
  const int col = t & 63;
  const int rp = t >> 6;
  const int gcol = blockIdx.x * 64 + col;
  for (int mb = blockIdx.y; mb < nbatch; mb += gridDim.y) {
    const int rbase = mb * 8;
    float a0[4] = {0.f, 0.f, 0.f, 0.f};
    float a1[4] = {0.f, 0.f, 0.f, 0.f};
    for (int kc = 0; kc < 8; ++kc) {
      __syncthreads();
      {
        int r = t >> 5, kl = (t & 31) * 8;
        int e = rbase + r;
        int row = list[e < cnt ? e : 0];
        int kg = kc * 256 + kl;
        const float* src = (kg < 1024) ? (x_t + (size_t)row * 1024 + kg)
                                       : (h_prev + (size_t)row * 1024 + (kg - 1024));
        floatx4 v0 = *reinterpret_cast<const floatx4*>(src);
        floatx4 v1 = *reinterpret_cast<const floatx4*>(src + 4);
        *reinterpret_cast<floatx4*>(&xr[r][kl]) = v0;
        *reinterpret_cast<floatx4*>(&xr[r][kl + 4]) = v1;
      }
      {
        const float* Wb = W_in + (size_t)(kc * 256) * 1024 + blockIdx.x * 64;
#pragma unroll
        for (int i = 0; i < 16; ++i) {
          int f = t + 256 * i;
          int k = f >> 4, c4 = (f & 15) << 2;
          floatx4 v = *reinterpret_cast<const floatx4*>(Wb + (size_t)k * 1024 + c4);
          *reinterpret_cast<floatx4*>(&Ws[k * 64 + c4]) = v;
        }
      }
      __syncthreads();
      const floatx4* x0v = reinterpret_cast<const floatx4*>(xr[rp * 2]);
      const floatx4* x1v = reinterpret_cast<const floatx4*>(xr[rp * 2 + 1]);
      for (int k4 = 0; k4 < 64; ++k4) {
        floatx4 xv0 = x0v[k4];
        floatx4 xv1 = x1v[k4];
        int kb = k4 * 4;
        float w0 = Ws[(kb + 0) * 64 + col];
        float w1 = Ws[(kb + 1) * 64 + col];
        float w2 = Ws[(kb + 2) * 64 + col];
        float w3 = Ws[(kb + 3) * 64 + col];
        a0[0] += xv0[0] * w0; a1[0] += xv1[0] * w0;
        a0[1] += xv0[1] * w1; a1[1] += xv1[1] * w1;
        a0[2] += xv0[2] * w2; a1[2] += xv1[2] * w2;
        a0[3] += xv0[3] * w3; a1[3] += xv1[3] * w3;
      }
    }
    float z0 = (a0[0] + a0[1]) + (a0[2] + a0[3]);
    float z1 = (a1[0] + a1[1]) + (a1[2] + a1[3]);
    int e0 = rbase + rp * 2, e1 = e0 + 1;
    if (e0 < cnt) scratch[(size_t)e0 * 1024 + gcol] = z0;
    if (e1 < cnt) scratch[(size_t)e1 * 1024 + gcol] = z1;
    __syncthreads();
  }
}

// ------- K4c: block-per-row: h=tanh(z+b) -> logits (ILP-8) -> argmax -> idx -------
__global__ __launch_bounds__(256) void k_fixB(const float* __restrict__ scratch, const float* __restrict__ b_in,
                                              const float* __restrict__ Wqs, const int* __restrict__ counter,
                                              const int* __restrict__ list, int* __restrict__ idx) {
  __shared__ float hrow[1024];
  __shared__ float partial[4 * 64];
  __shared__ float lg[64];
  const int t = threadIdx.x;
  const int cnt = min(counter[0], FIX_CAP);
  const int e = blockIdx.x;
  if (e >= cnt) return;
  const int r = list[e];
  const int n4 = t * 4;
  floatx4 b4 = *reinterpret_cast<const floatx4*>(&b_in[n4]);
  floatx4 z4 = *reinterpret_cast<const floatx4*>(&scratch[(size_t)e * 1024 + n4]);
  hrow[n4 + 0] = tanhf(z4[0] + b4[0]);
  hrow[n4 + 1] = tanhf(z4[1] + b4[1]);
  hrow[n4 + 2] = tanhf(z4[2] + b4[2]);
  hrow[n4 + 3] = tanhf(z4[3] + b4[3]);
  __syncthreads();
  const int s = t & 63, part = t >> 6;
  const int hb0 = part * 256;
  const float* Wp = Wqs + (size_t)hb0 * 64 + s;
  float p0 = 0.f, p1 = 0.f, p2 = 0.f, p3 = 0.f, p4 = 0.f, p5 = 0.f, p6 = 0.f, p7 = 0.f;
  for (int h8 = 0; h8 < 256; h8 += 8) {
    float w0 = Wp[(size_t)(h8 + 0) * 64];
    float w1 = Wp[(size_t)(h8 + 1) * 64];
    float w2 = Wp[(size_t)(h8 + 2) * 64];
    float w3 = Wp[(size_t)(h8 + 3) * 64];
    float w4 = Wp[(size_t)(h8 + 4) * 64];
    float w5 = Wp[(size_t)(h8 + 5) * 64];
    float w6 = Wp[(size_t)(h8 + 6) * 64];
    float w7 = Wp[(size_t)(h8 + 7) * 64];
    const int hb = hb0 + h8;
    p0 += hrow[hb + 0] * w0;
    p1 += hrow[hb + 1] * w1;
    p2 += hrow[hb + 2] * w2;
    p3 += hrow[hb + 3] * w3;
    p4 += hrow[hb + 4] * w4;
    p5 += hrow[hb + 5] * w5;
    p6 += hrow[hb + 6] * w6;
    p7 += hrow[hb + 7] * w7;
  }
  partial[part * 64 + s] = ((p0 + p1) + (p2 + p3)) + ((p4 + p5) + (p6 + p7));
  __syncthreads();
  if (t < 64) lg[t] = partial[t] + partial[64 + t] + partial[128 + t] + partial[192 + t] + Wqs[1024 * 64 + t];
  __syncthreads();
  if (t == 0) {
    float bv = lg[0]; int bi = 0;
    for (int ss = 1; ss < 64; ++ss) {
      if (lg[ss] > bv) { bv = lg[ss]; bi = ss; }
    }
    idx[r] = bi;
  }
}

// ---------------- K5: mixture: angles -> cos -> m_t (block per row, h from A2 f16) --------
__global__ __launch_bounds__(256) void k_mix(const _Float16* __restrict__ A2h, const int* __restrict__ idx,
                                             const float* __restrict__ Wm_enc, const float* __restrict__ theta,
                                             const float* __restrict__ Wm_dec, const float* __restrict__ b_m,
                                             _Float16* __restrict__ A2) {
  __shared__ float hrow[1024];
  __shared__ float partial[256];
  __shared__ float expz[16];
  const int b = blockIdx.x, t = threadIdx.x;
  const int s = idx[b];
  {
    half4 v = *reinterpret_cast<const half4*>(&A2h[(size_t)b * 2048 + t * 4]);
    hrow[t * 4 + 0] = (float)v[0];
    hrow[t * 4 + 1] = (float)v[1];
    hrow[t * 4 + 2] = (float)v[2];
    hrow[t * 4 + 3] = (float)v[3];
  }
  __syncthreads();
  const int q = t & 15, g = t >> 4;
  const float* We = Wm_enc + (size_t)s * 16384;
  float p = 0.f;
#pragma unroll 8
  for (int j = 0; j < 64; ++j) {
    int h = g + j * 16;
    p += hrow[h] * We[h * 16 + q];
  }
  partial[t] = p;
  __syncthreads();
  if (t < 16) {
    float a = 0.f;
#pragma unroll
    for (int g2 = 0; g2 < 16; ++g2) a += partial[g2 * 16 + t];
    a += theta[s * 16 + t];
    expz[t] = cosf(a);
  }
  __syncthreads();
  const float* Wd = Wm_dec + (size_t)s * 16384;
  float e[16];
#pragma unroll
  for (int qq = 0; qq < 16; ++qq) e[qq] = expz[qq];
#pragma unroll
  for (int r = 0; r < 4; ++r) {
    int h = r * 256 + t;
    float v = b_m[h];
#pragma unroll
    for (int qq = 0; qq < 16; ++qq) v += e[qq] * Wd[qq * 1024 + h];
    A2[(size_t)b * 2048 + 1024 + h] = f2h(tanhf(v));
  }
}

// ---------------- K6: goh = A2 @ BT^T + b_og -> tanh/split epilogue, fp16 MFMA ----------------
// 128x128 tile, BK=32, R12/R14 config (measured floor).
__global__ __launch_bounds__(256) void k_gemm4h(const _Float16* __restrict__ A2,
                                                const _Float16* __restrict__ BT,
                                                const float* __restrict__ b_og, float* __restrict__ out) {
  __shared__ __align__(16) _Float16 As[4 * 4096];  // 32KB
  __shared__ __align__(16) _Float16 Bs[4 * 4096];  // 32KB
  const int t = threadIdx.x;
  const int lane = t & 63, w = t >> 6;
  const int wm = w >> 1, wn = w & 1;
  const int m0 = blockIdx.x * 128, n0 = blockIdx.y * 128;
  const int lr = lane & 15, lk = lane >> 4;
  floatx4 acc[4][4];
  floatx4 zero = {0.f, 0.f, 0.f, 0.f};
#pragma unroll
  for (int mi = 0; mi < 4; ++mi)
#pragma unroll
    for (int ni = 0; ni < 4; ++ni) acc[mi][ni] = zero;

  auto stage = [&](int p, int kt) {   // 4 GLL per thread
    const int k0 = kt * 32;
#pragma unroll
    for (int j = 0; j < 2; ++j) {
      int cc = j * 256 + t;
      int row = cc >> 2, sl = cc & 3;
      int sg = sl ^ ((row >> 1) & 3);
      size_t ga = (size_t)(m0 + row) * 2048 + k0 + sg * 8;
      size_t gb = (size_t)(n0 + row) * 2048 + k0 + sg * 8;
      GLL(A2 + ga, &As[p * 4096 + cc * 8]);
      GLL(BT + gb, &Bs[p * 4096 + cc * 8]);
    }
  };
  auto compute = [&](int p) {
    half8 af[4], bf[4];
#pragma unroll
    for (int mi = 0; mi < 4; ++mi) {
      int row = wm * 64 + mi * 16 + lr;
      int sl = lk ^ ((row >> 1) & 3);
      af[mi] = *reinterpret_cast<const half8*>(&As[p * 4096 + row * 32 + sl * 8]);
    }
#pragma unroll
    for (int ni = 0; ni < 4; ++ni) {
      int row = wn * 64 + ni * 16 + lr;
      int sl = lk ^ ((row >> 1) & 3);
      bf[ni] = *reinterpret_cast<const half8*>(&Bs[p * 4096 + row * 32 + sl * 8]);
    }
#pragma unroll
    for (int mi = 0; mi < 4; ++mi)
#pragma unroll
      for (int ni = 0; ni < 4; ++ni)
        acc[mi][ni] = __builtin_amdgcn_mfma_f32_16x16x32_f16(af[mi], bf[ni], acc[mi][ni], 0, 0, 0);
  };

  stage(0, 0);
  stage(1, 1);
  stage(2, 2);
  for (int kt = 0; kt < 64; ++kt) {
    __builtin_amdgcn_sched_barrier(0);
    if (kt < 62) {
      asm volatile("s_waitcnt vmcnt(8)" ::: "memory");
    } else if (kt == 62) {
      asm volatile("s_waitcnt vmcnt(4)" ::: "memory");
    } else {
      asm volatile("s_waitcnt vmcnt(0)" ::: "memory");
    }
    __builtin_amdgcn_s_barrier();
    __builtin_amdgcn_sched_barrier(0);
    if (kt + 3 < 64) stage((kt + 3) & 3, kt + 3);
    compute(kt & 3);
  }

#pragma unroll
  for (int mi = 0; mi < 4; ++mi) {
#pragma unroll
    for (int ni = 0; ni < 4; ++ni) {
      int gn = n0 + wn * 64 + ni * 16 + lr;
      float bias = b_og[gn];
      int gmb = m0 + wm * 64 + mi * 16 + lk * 4;
#pragma unroll
      for (int j = 0; j < 4; ++j) {
        int gm = gmb + j;
        float v = acc[mi][ni][j] + bias;
        if (gn < 1024) {
          out[OUT_H_OFF + (size_t)gm * 1024 + gn] = tanhf(v);  // h_next
        } else {
          out[(size_t)gm * 1024 + (gn - 1024)] = v;            // y_t
        }
      }
    }
  }
}

extern "C" void kernel_launch(void* const* d_in, const int* in_sizes, int n_in,
                              void* d_out, int out_size, void* d_ws, size_t ws_size,
                              hipStream_t stream) {
  (void)in_sizes; (void)n_in; (void)out_size;
  const float* x_t    = (const float*)d_in[0];
  const float* h_prev = (const float*)d_in[1];
  const float* W_in   = (const float*)d_in[2];
  const float* b_in   = (const float*)d_in[3];
  const float* W_q    = (const float*)d_in[4];
  const float* b_q    = (const float*)d_in[5];
  const float* W_sel  = (const float*)d_in[6];
  const float* b_sel  = (const float*)d_in[7];
  const float* Wm_enc = (const float*)d_in[8];
  const float* theta  = (const float*)d_in[9];
  const float* Wm_dec = (const float*)d_in[10];
  const float* b_m    = (const float*)d_in[11];
  const float* W_og   = (const float*)d_in[12];
  const float* b_og   = (const float*)d_in[13];
  float* out = (float*)d_out;

  char* ws = (char*)d_ws;
  _Float16* A2          = (_Float16*)(ws + ((size_t)16 << 20));
  _Float16* BT          = (_Float16*)(ws + ((size_t)32 << 20));
  float* Wqs            = (float*)(ws + ((size_t)40 << 20));
  int* idx              = (int*)(ws + ((size_t)41 << 20));
  int* counter          = (int*)(ws + ((size_t)41 << 20) + 16384);
  int* list             = (int*)(ws + ((size_t)41 << 20) + 16384 + 64);
  _Float16* A1          = (_Float16*)(ws + ((size_t)42 << 20));
  _Float16* BTin        = (_Float16*)(ws + ((size_t)58 << 20));
  float* fix_scratch    = (float*)(ws + ((size_t)62 << 20));

  const bool use_mfma = ws_size >= ((size_t)82 << 20);

  hipLaunchKernelGGL(k_transpose, dim3(32, 32), dim3(256), 0, stream, W_og, BT);
  hipLaunchKernelGGL(k_wqs, dim3(257), dim3(256), 0, stream, W_q, b_q, W_sel, b_sel, Wqs);
  hipMemsetAsync(counter, 0, 4, stream);

  if (use_mfma) {
    hipLaunchKernelGGL(k_convA, dim3(2048), dim3(256), 0, stream, x_t, h_prev, A1);
    hipLaunchKernelGGL(k_convB, dim3(32, 16), dim3(256), 0, stream, W_in, BTin);
    hipLaunchKernelGGL(k_gemm1h, dim3(32, 16), dim3(256), 0, stream,
                       A1, BTin, b_in, A2);
    hipLaunchKernelGGL(k_argmax, dim3(256), dim3(256), 0, stream, A2, Wqs, idx, counter, list, TAU);
    hipLaunchKernelGGL(k_fixA3, dim3(16, 32), dim3(256), 0, stream,
                       x_t, h_prev, W_in, counter, list, fix_scratch);
    hipLaunchKernelGGL(k_fixB, dim3(FIX_CAP), dim3(256), 0, stream,
                       fix_scratch, b_in, Wqs, counter, list, idx);
  } else {
    hipLaunchKernelGGL(k_gemm1, dim3(32, 16), dim3(256), 0, stream, x_t, h_prev, W_in, b_in, A2);
    hipLaunchKernelGGL(k_argmax, dim3(256), dim3(256), 0, stream, A2, Wqs, idx, counter, list, 0.0f);
  }

  hipLaunchKernelGGL(k_mix, dim3(4096), dim3(256), 0, stream, A2, idx, Wm_enc, theta, Wm_dec, b_m, A2);
  hipLaunchKernelGGL(k_gemm4h, dim3(32, 16), dim3(256), 0, stream, A2, BT, b_og, out);
}

// Round 18
// 249.415 us; speedup vs baseline: 1.2652x; 1.0187x over previous
//
#include <hip/hip_runtime.h>
#include <math.h>

// Shapes: B=4096, IN=1024, H=1024, S=64, Q=16, OUT=1024
// ws layout:
//   [16,32MB)   A2 f16 [4096][2048]  (cols 0-1023 = h_int f16, 1024-2047 = m_t)
//   [32,40MB)   BT f16 [2048][2048]  (= W_og^T)
//   [40,41MB)   Wqs f32 [1025][64]
//   [41MB)      idx int[4096]; counter; list
//   [42,58MB)   A1 f16 [4096][2048]  ([x|h] converted)
//   [58,62MB)   BTin f16 [1024][2048] (W_in^T)
//   [62,78MB)   fix_scratch f32 [FIX_CAP][1024]

typedef __attribute__((ext_vector_type(4))) float floatx4;
typedef __attribute__((ext_vector_type(8))) _Float16 half8;
typedef __attribute__((ext_vector_type(4))) _Float16 half4;

#define OUT_H_OFF 4194304
#define TAU 4e-3f
#define FIX_CAP 512

#define AS1 __attribute__((address_space(1)))
#define AS3 __attribute__((address_space(3)))
#define GLL(gptr, lptr) __builtin_amdgcn_global_load_lds((const AS1 void*)(gptr), (AS3 void*)(lptr), 16, 0, 0)

__device__ __forceinline__ _Float16 f2h(float f) { return (_Float16)f; }  // v_cvt_f16_f32, RNE

// ---------------- K1: BT[n][k] = f16(W_og[k][n]), 2048x2048 ----------------
__global__ __launch_bounds__(256) void k_transpose(const float* __restrict__ W,
                                                   _Float16* __restrict__ BT) {
  __shared__ float tile[64][65];
  const int k0 = blockIdx.x * 64, n0 = blockIdx.y * 64;
  const int t = threadIdx.x, c = t & 63, rr = t >> 6;
#pragma unroll
  for (int i = 0; i < 16; ++i) {
    int r = i * 4 + rr;
    tile[r][c] = W[(size_t)(k0 + r) * 2048 + n0 + c];
  }
  __syncthreads();
#pragma unroll
  for (int i = 0; i < 16; ++i) {
    int r = i * 4 + rr;  // n-local
    BT[(size_t)(n0 + r) * 2048 + k0 + c] = f2h(tile[c][r]);
  }
}

// ---------------- K1b: convert A = [x|h] -> A1 f16 [4096][2048] --------
__global__ __launch_bounds__(256) void k_convA(const float* __restrict__ x_t, const float* __restrict__ h_prev,
                                               _Float16* __restrict__ A1) {
  const int stride = gridDim.x * blockDim.x;
  for (int c = blockIdx.x * blockDim.x + threadIdx.x; c < 2097152; c += stride) {
    int m = c >> 9, kc = (c & 511) << 2;
    const float* src = (kc < 1024) ? (x_t + (size_t)m * 1024 + kc)
                                   : (h_prev + (size_t)m * 1024 + (kc - 1024));
    floatx4 v = *reinterpret_cast<const floatx4*>(src);
    half4 h = {f2h(v[0]), f2h(v[1]), f2h(v[2]), f2h(v[3])};
    *reinterpret_cast<half4*>(&A1[(size_t)m * 2048 + kc]) = h;
  }
}

// ------- K1c: convert+transpose W_in [2048][1024] -> BTin f16 [1024][2048] -------
__global__ __launch_bounds__(256) void k_convB(const float* __restrict__ W_in,
                                               _Float16* __restrict__ BTin) {
  __shared__ float tile[64][65];
  const int k0 = blockIdx.x * 64, n0 = blockIdx.y * 64;
  const int t = threadIdx.x, c = t & 63, rr = t >> 6;
#pragma unroll
  for (int i = 0; i < 16; ++i) {
    int r = i * 4 + rr;
    tile[r][c] = W_in[(size_t)(k0 + r) * 1024 + n0 + c];
  }
  __syncthreads();
#pragma unroll
  for (int i = 0; i < 16; ++i) {
    int r = i * 4 + rr;  // n-local
    BTin[(size_t)(n0 + r) * 2048 + k0 + c] = f2h(tile[c][r]);
  }
}

// -------- K2h: A2[:, :1024] = f16(tanh(A1 @ W_in + b_in)), fp16 MFMA --------
// BM=128, BN=64, BK=32, K=2048 -> 64 steps. R12/R14 config (measured floor).
__global__ __launch_bounds__(256) void k_gemm1h(const _Float16* __restrict__ A1,
                                                const _Float16* __restrict__ BTin,
                                                const float* __restrict__ b_in,
                                                _Float16* __restrict__ A2) {
  __shared__ __align__(16) _Float16 As[4 * 4096];  // [buf][128*32] = 32KB
  __shared__ __align__(16) _Float16 Bs[4 * 2048];  // [buf][64*32]  = 16KB
  const int t = threadIdx.x;
  const int lane = t & 63, w = t >> 6;
  const int wm = w >> 1, wn = w & 1;
  const int m0 = blockIdx.x * 128, n0 = blockIdx.y * 64;
  const int lr = lane & 15, lk = lane >> 4;
  floatx4 acc[4][2];
  floatx4 zero = {0.f, 0.f, 0.f, 0.f};
#pragma unroll
  for (int mi = 0; mi < 4; ++mi)
#pragma unroll
    for (int ni = 0; ni < 2; ++ni) acc[mi][ni] = zero;

  auto stage = [&](int p, int kt) {   // 3 GLL per thread
    const int k0 = kt * 32;
#pragma unroll
    for (int j = 0; j < 2; ++j) {
      int cc = j * 256 + t;
      int row = cc >> 2, sl = cc & 3;
      int sg = sl ^ ((row >> 1) & 3);
      size_t ga = (size_t)(m0 + row) * 2048 + k0 + sg * 8;
      GLL(A1 + ga, &As[p * 4096 + cc * 8]);
    }
    {
      int cc = t;
      int row = cc >> 2, sl = cc & 3;
      int sg = sl ^ ((row >> 1) & 3);
      size_t gb = (size_t)(n0 + row) * 2048 + k0 + sg * 8;
      GLL(BTin + gb, &Bs[p * 2048 + cc * 8]);
    }
  };
  auto compute = [&](int p) {
    half8 af[4], bf[2];
#pragma unroll
    for (int mi = 0; mi < 4; ++mi) {
      int row = wm * 64 + mi * 16 + lr;
      int sl = lk ^ ((row >> 1) & 3);
      af[mi] = *reinterpret_cast<const half8*>(&As[p * 4096 + row * 32 + sl * 8]);
    }
#pragma unroll
    for (int ni = 0; ni < 2; ++ni) {
      int row = wn * 32 + ni * 16 + lr;
      int sl = lk ^ ((row >> 1) & 3);
      bf[ni] = *reinterpret_cast<const half8*>(&Bs[p * 2048 + row * 32 + sl * 8]);
    }
#pragma unroll
    for (int mi = 0; mi < 4; ++mi)
#pragma unroll
      for (int ni = 0; ni < 2; ++ni)
        acc[mi][ni] = __builtin_amdgcn_mfma_f32_16x16x32_f16(af[mi], bf[ni], acc[mi][ni], 0, 0, 0);
  };

  stage(0, 0);
  stage(1, 1);
  stage(2, 2);
  for (int kt = 0; kt < 64; ++kt) {
    __builtin_amdgcn_sched_barrier(0);
    if (kt < 62) {
      asm volatile("s_waitcnt vmcnt(6)" ::: "memory");
    } else if (kt == 62) {
      asm volatile("s_waitcnt vmcnt(3)" ::: "memory");
    } else {
      asm volatile("s_waitcnt vmcnt(0)" ::: "memory");
    }
    __builtin_amdgcn_s_barrier();
    __builtin_amdgcn_sched_barrier(0);
    if (kt + 3 < 64) stage((kt + 3) & 3, kt + 3);
    compute(kt & 3);
  }

#pragma unroll
  for (int mi = 0; mi < 4; ++mi) {
#pragma unroll
    for (int ni = 0; ni < 2; ++ni) {
      int gn = n0 + wn * 32 + ni * 16 + lr;
      float bias = b_in[gn];
      int gmb = m0 + wm * 64 + mi * 16 + lk * 4;
#pragma unroll
      for (int j = 0; j < 4; ++j) {
        int gm = gmb + j;
        A2[(size_t)gm * 2048 + gn] = f2h(tanhf(acc[mi][ni][j] + bias));
      }
    }
  }
}

// ---------------- K2f: fp32 fallback GEMM1 (used when ws too small) ----------------
__global__ __launch_bounds__(256) void k_gemm1(const float* __restrict__ x_t, const float* __restrict__ h_prev,
                                               const float* __restrict__ W_in, const float* __restrict__ b_in,
                                               _Float16* __restrict__ A2) {
  __shared__ float As[16 * 128];
  __shared__ float Bs[16 * 64];
  const int t = threadIdx.x;
  const int m0 = blockIdx.x * 128, n0 = blockIdx.y * 64;
  const int ty = t >> 4, tx = t & 15;
  float acc[8][4];
#pragma unroll
  for (int i = 0; i < 8; ++i)
#pragma unroll
    for (int j = 0; j < 4; ++j) acc[i][j] = 0.f;
  for (int kt = 0; kt < 128; ++kt) {
    const int k0 = kt * 16;
    __syncthreads();
#pragma unroll
    for (int u = 0; u < 2; ++u) {
      int cc = t + u * 256;
      int row = cc >> 2, col4 = (cc & 3) << 2;
      int gk = k0 + col4;
      const float* src = (gk < 1024) ? (x_t + (size_t)(m0 + row) * 1024 + gk)
                                     : (h_prev + (size_t)(m0 + row) * 1024 + (gk - 1024));
      floatx4 v = *reinterpret_cast<const floatx4*>(src);
      As[(col4 + 0) * 128 + row] = v[0];
      As[(col4 + 1) * 128 + row] = v[1];
      As[(col4 + 2) * 128 + row] = v[2];
      As[(col4 + 3) * 128 + row] = v[3];
    }
    {
      int kr = t >> 4, c4 = (t & 15) << 2;
      *reinterpret_cast<floatx4*>(&Bs[kr * 64 + c4]) =
          *reinterpret_cast<const floatx4*>(&W_in[(size_t)(k0 + kr) * 1024 + n0 + c4]);
    }
    __syncthreads();
#pragma unroll
    for (int kk = 0; kk < 16; ++kk) {
      floatx4 a0 = *reinterpret_cast<const floatx4*>(&As[kk * 128 + ty * 8]);
      floatx4 a1 = *reinterpret_cast<const floatx4*>(&As[kk * 128 + ty * 8 + 4]);
      floatx4 b = *reinterpret_cast<const floatx4*>(&Bs[kk * 64 + tx * 4]);
#pragma unroll
      for (int j = 0; j < 4; ++j) {
        acc[0][j] += a0[0] * b[j]; acc[1][j] += a0[1] * b[j];
        acc[2][j] += a0[2] * b[j]; acc[3][j] += a0[3] * b[j];
        acc[4][j] += a1[0] * b[j]; acc[5][j] += a1[1] * b[j];
        acc[6][j] += a1[2] * b[j]; acc[7][j] += a1[3] * b[j];
      }
    }
  }
  const int nbase = n0 + tx * 4;
  floatx4 bias = *reinterpret_cast<const floatx4*>(&b_in[nbase]);
#pragma unroll
  for (int i = 0; i < 8; ++i) {
    int gm = m0 + ty * 8 + i;
    half4 pk;
#pragma unroll
    for (int j = 0; j < 4; ++j) pk[j] = f2h(tanhf(acc[i][j] + bias[j]));
    *reinterpret_cast<half4*>(&A2[(size_t)gm * 2048 + nbase]) = pk;
  }
}

// ---------------- K3: Wqs = W_q @ W_sel (+ fused bias row 1024), ILP-8 ----------------
__global__ __launch_bounds__(256) void k_wqs(const float* __restrict__ W_q, const float* __restrict__ b_q,
                                             const float* __restrict__ W_sel, const float* __restrict__ b_sel,
                                             float* __restrict__ Wqs) {
  const int t = threadIdx.x;
  const int w = t >> 6, lane = t & 63;
  const int h = blockIdx.x * 4 + w;
  if (h > 1024) return;
  const float* src = (h < 1024) ? (W_q + (size_t)h * 1024) : b_q;
  const float* Wp = W_sel + lane;
  float a0 = 0.f, a1 = 0.f, a2 = 0.f, a3 = 0.f, a4 = 0.f, a5 = 0.f, a6 = 0.f, a7 = 0.f;
  for (int j = 0; j < 1024; j += 8) {
    floatx4 v0 = *reinterpret_cast<const floatx4*>(&src[j]);
    floatx4 v1 = *reinterpret_cast<const floatx4*>(&src[j + 4]);
    float w0 = Wp[(size_t)(j + 0) * 64];
    float w1 = Wp[(size_t)(j + 1) * 64];
    float w2 = Wp[(size_t)(j + 2) * 64];
    float w3 = Wp[(size_t)(j + 3) * 64];
    float w4 = Wp[(size_t)(j + 4) * 64];
    float w5 = Wp[(size_t)(j + 5) * 64];
    float w6 = Wp[(size_t)(j + 6) * 64];
    float w7 = Wp[(size_t)(j + 7) * 64];
    a0 += v0[0] * w0;
    a1 += v0[1] * w1;
    a2 += v0[2] * w2;
    a3 += v0[3] * w3;
    a4 += v1[0] * w4;
    a5 += v1[1] * w5;
    a6 += v1[2] * w6;
    a7 += v1[3] * w7;
  }
  float acc = ((a0 + a1) + (a2 + a3)) + ((a4 + a5) + (a6 + a7));
  if (h == 1024) acc += b_sel[lane];
  Wqs[(size_t)h * 64 + lane] = acc;
}

// ------- K4: logits = h(f16) @ Wqs + bqs; argmax; flag gap<TAU. 8 rows/block, 512 blocks -------
__global__ __launch_bounds__(256) void k_argmax(const _Float16* __restrict__ A2, const float* __restrict__ Wqs,
                                                int* __restrict__ idx, int* __restrict__ counter,
                                                int* __restrict__ list, float tau) {
  __shared__ float Ahs[64 * 17];  // [k][r] stride 17 (rows 0..7 used)
  __shared__ float Wt[64 * 64];   // [k][s]
  const int t = threadIdx.x;
  const int r0 = blockIdx.x * 8;
  const int w = t >> 6, lane = t & 63;
  float acc[2] = {0.f, 0.f};

  for (int kt = 0; kt < 16; ++kt) {
    const int k0 = kt * 64;
    __syncthreads();
    if (t < 64) {                      // stage 8 rows x 64 k of f16 h
      int r = t >> 3, k8 = (t & 7) * 8;
      half8 v = *reinterpret_cast<const half8*>(&A2[(size_t)(r0 + r) * 2048 + k0 + k8]);
#pragma unroll
      for (int j = 0; j < 8; ++j) Ahs[(k8 + j) * 17 + r] = (float)v[j];
    }
#pragma unroll
    for (int u = 0; u < 4; ++u) {
      int cc = t + u * 256;
      int kr = cc >> 4, c4 = (cc & 15) << 2;
      *reinterpret_cast<floatx4*>(&Wt[kr * 64 + c4]) =
          *reinterpret_cast<const floatx4*>(&Wqs[(size_t)(k0 + kr) * 64 + c4]);
    }
    __syncthreads();
#pragma unroll
    for (int k = 0; k < 64; ++k) {
      float wv = Wt[k * 64 + lane];
      const float* ar = &Ahs[k * 17 + w * 2];   // wave-uniform -> broadcast
      acc[0] += ar[0] * wv;
      acc[1] += ar[1] * wv;
    }
  }
  const float bqs = Wqs[1024 * 64 + lane];
#pragma unroll
  for (int i = 0; i < 2; ++i) {
    float v1 = acc[i] + bqs;
    int i1 = lane;
    float v2 = -__builtin_inff();
#pragma unroll
    for (int off = 32; off >= 1; off >>= 1) {
      float ov1 = __shfl_xor(v1, off);
      int oi1 = __shfl_xor(i1, off);
      float ov2 = __shfl_xor(v2, off);
      if (ov1 > v1 || (ov1 == v1 && oi1 < i1)) {
        v2 = fmaxf(v1, ov2); v1 = ov1; i1 = oi1;
      } else {
        v2 = fmaxf(v2, ov1);
      }
    }
    if (lane == 0) {
      int row = r0 + w * 2 + i;
      idx[row] = i1;
      if (v1 - v2 < tau) {
        int pos = atomicAdd(counter, 1);
        if (pos < FIX_CAP) list[pos] = row;
      }
    }
  }
}

// ------- K4b: batched exact fp32 z, LDS-staged W -------
__global__ __launch_bounds__(256) void k_fixA3(const float* __restrict__ x_t, const float* __restrict__ h_prev,
                                               const float* __restrict__ W_in, const int* __restrict__ counter,
                                               const int* __restrict__ list, float* __restrict__ scratch) {
  __shared__ float Ws[256 * 64];   // [k][col] 64KB
  __shared__ float xr[8][260];
  const int t = threadIdx.x;
  const int cnt = min(counter[0], FIX_CAP);
  const int nbatch = (cnt + 7) >> 3;
  const int col = t & 63;
  const int rp = t >> 6;
  const int gcol = blockIdx.x * 64 + col;
  for (int mb = blockIdx.y; mb < nbatch; mb += gridDim.y) {
    const int rbase = mb * 8;
    float a0[4] = {0.f, 0.f, 0.f, 0.f};
    float a1[4] = {0.f, 0.f, 0.f, 0.f};
    for (int kc = 0; kc < 8; ++kc) {
      __syncthreads();
      {
        int r = t >> 5, kl = (t & 31) * 8;
        int e = rbase + r;
        int row = list[e < cnt ? e : 0];
        int kg = kc * 256 + kl;
        const float* src = (kg < 1024) ? (x_t + (size_t)row * 1024 + kg)
                                       : (h_prev + (size_t)row * 1024 + (kg - 1024));
        floatx4 v0 = *reinterpret_cast<const floatx4*>(src);
        floatx4 v1 = *reinterpret_cast<const floatx4*>(src + 4);
        *reinterpret_cast<floatx4*>(&xr[r][kl]) = v0;
        *reinterpret_cast<floatx4*>(&xr[r][kl + 4]) = v1;
      }
      {
        const float* Wb = W_in + (size_t)(kc * 256) * 1024 + blockIdx.x * 64;
#pragma unroll
        for (int i = 0; i < 16; ++i) {
          int f = t + 256 * i;
          int k = f >> 4, c4 = (f & 15) << 2;
          floatx4 v = *reinterpret_cast<const floatx4*>(Wb + (size_t)k * 1024 + c4);
          *reinterpret_cast<floatx4*>(&Ws[k * 64 + c4]) = v;
        }
      }
      __syncthreads();
      const floatx4* x0v = reinterpret_cast<const floatx4*>(xr[rp * 2]);
      const floatx4* x1v = reinterpret_cast<const floatx4*>(xr[rp * 2 + 1]);
      for (int k4 = 0; k4 < 64; ++k4) {
        floatx4 xv0 = x0v[k4];
        floatx4 xv1 = x1v[k4];
        int kb = k4 * 4;
        float w0 = Ws[(kb + 0) * 64 + col];
        float w1 = Ws[(kb + 1) * 64 + col];
        float w2 = Ws[(kb + 2) * 64 + col];
        float w3 = Ws[(kb + 3) * 64 + col];
        a0[0] += xv0[0] * w0; a1[0] += xv1[0] * w0;
        a0[1] += xv0[1] * w1; a1[1] += xv1[1] * w1;
        a0[2] += xv0[2] * w2; a1[2] += xv1[2] * w2;
        a0[3] += xv0[3] * w3; a1[3] += xv1[3] * w3;
      }
    }
    float z0 = (a0[0] + a0[1]) + (a0[2] + a0[3]);
    float z1 = (a1[0] + a1[1]) + (a1[2] + a1[3]);
    int e0 = rbase + rp * 2, e1 = e0 + 1;
    if (e0 < cnt) scratch[(size_t)e0 * 1024 + gcol] = z0;
    if (e1 < cnt) scratch[(size_t)e1 * 1024 + gcol] = z1;
    __syncthreads();
  }
}

// ------- K4c: block-per-row: h=tanh(z+b) -> logits (ILP-8) -> argmax -> idx -------
__global__ __launch_bounds__(256) void k_fixB(const float* __restrict__ scratch, const float* __restrict__ b_in,
                                              const float* __restrict__ Wqs, const int* __restrict__ counter,
                                              const int* __restrict__ list, int* __restrict__ idx) {
  __shared__ float hrow[1024];
  __shared__ float partial[4 * 64];
  __shared__ float lg[64];
  const int t = threadIdx.x;
  const int cnt = min(counter[0], FIX_CAP);
  const int e = blockIdx.x;
  if (e >= cnt) return;
  const int r = list[e];
  const int n4 = t * 4;
  floatx4 b4 = *reinterpret_cast<const floatx4*>(&b_in[n4]);
  floatx4 z4 = *reinterpret_cast<const floatx4*>(&scratch[(size_t)e * 1024 + n4]);
  hrow[n4 + 0] = tanhf(z4[0] + b4[0]);
  hrow[n4 + 1] = tanhf(z4[1] + b4[1]);
  hrow[n4 + 2] = tanhf(z4[2] + b4[2]);
  hrow[n4 + 3] = tanhf(z4[3] + b4[3]);
  __syncthreads();
  const int s = t & 63, part = t >> 6;
  const int hb0 = part * 256;
  const float* Wp = Wqs + (size_t)hb0 * 64 + s;
  float p0 = 0.f, p1 = 0.f, p2 = 0.f, p3 = 0.f, p4 = 0.f, p5 = 0.f, p6 = 0.f, p7 = 0.f;
  for (int h8 = 0; h8 < 256; h8 += 8) {
    float w0 = Wp[(size_t)(h8 + 0) * 64];
    float w1 = Wp[(size_t)(h8 + 1) * 64];
    float w2 = Wp[(size_t)(h8 + 2) * 64];
    float w3 = Wp[(size_t)(h8 + 3) * 64];
    float w4 = Wp[(size_t)(h8 + 4) * 64];
    float w5 = Wp[(size_t)(h8 + 5) * 64];
    float w6 = Wp[(size_t)(h8 + 6) * 64];
    float w7 = Wp[(size_t)(h8 + 7) * 64];
    const int hb = hb0 + h8;
    p0 += hrow[hb + 0] * w0;
    p1 += hrow[hb + 1] * w1;
    p2 += hrow[hb + 2] * w2;
    p3 += hrow[hb + 3] * w3;
    p4 += hrow[hb + 4] * w4;
    p5 += hrow[hb + 5] * w5;
    p6 += hrow[hb + 6] * w6;
    p7 += hrow[hb + 7] * w7;
  }
  partial[part * 64 + s] = ((p0 + p1) + (p2 + p3)) + ((p4 + p5) + (p6 + p7));
  __syncthreads();
  if (t < 64) lg[t] = partial[t] + partial[64 + t] + partial[128 + t] + partial[192 + t] + Wqs[1024 * 64 + t];
  __syncthreads();
  if (t == 0) {
    float bv = lg[0]; int bi = 0;
    for (int ss = 1; ss < 64; ++ss) {
      if (lg[ss] > bv) { bv = lg[ss]; bi = ss; }
    }
    idx[r] = bi;
  }
}

// ---------------- K5: mixture: angles -> cos -> m_t (block per row, h from A2 f16) --------
__global__ __launch_bounds__(256) void k_mix(const _Float16* __restrict__ A2h, const int* __restrict__ idx,
                                             const float* __restrict__ Wm_enc, const float* __restrict__ theta,
                                             const float* __restrict__ Wm_dec, const float* __restrict__ b_m,
                                             _Float16* __restrict__ A2) {
  __shared__ float hrow[1024];
  __shared__ float partial[256];
  __shared__ float expz[16];
  const int b = blockIdx.x, t = threadIdx.x;
  const int s = idx[b];
  {
    half4 v = *reinterpret_cast<const half4*>(&A2h[(size_t)b * 2048 + t * 4]);
    hrow[t * 4 + 0] = (float)v[0];
    hrow[t * 4 + 1] = (float)v[1];
    hrow[t * 4 + 2] = (float)v[2];
    hrow[t * 4 + 3] = (float)v[3];
  }
  __syncthreads();
  const int q = t & 15, g = t >> 4;
  const float* We = Wm_enc + (size_t)s * 16384;
  float p = 0.f;
#pragma unroll 8
  for (int j = 0; j < 64; ++j) {
    int h = g + j * 16;
    p += hrow[h] * We[h * 16 + q];
  }
  partial[t] = p;
  __syncthreads();
  if (t < 16) {
    float a = 0.f;
#pragma unroll
    for (int g2 = 0; g2 < 16; ++g2) a += partial[g2 * 16 + t];
    a += theta[s * 16 + t];
    expz[t] = cosf(a);
  }
  __syncthreads();
  const float* Wd = Wm_dec + (size_t)s * 16384;
  float e[16];
#pragma unroll
  for (int qq = 0; qq < 16; ++qq) e[qq] = expz[qq];
#pragma unroll
  for (int r = 0; r < 4; ++r) {
    int h = r * 256 + t;
    float v = b_m[h];
#pragma unroll
    for (int qq = 0; qq < 16; ++qq) v += e[qq] * Wd[qq * 1024 + h];
    A2[(size_t)b * 2048 + 1024 + h] = f2h(tanhf(v));
  }
}

// ---------------- K6: goh = A2 @ BT^T + b_og -> tanh/split epilogue, fp16 MFMA ----------------
// 128x128 tile, BK=32, R12/R14 config (measured floor).
__global__ __launch_bounds__(256) void k_gemm4h(const _Float16* __restrict__ A2,
                                                const _Float16* __restrict__ BT,
                                                const float* __restrict__ b_og, float* __restrict__ out) {
  __shared__ __align__(16) _Float16 As[4 * 4096];  // 32KB
  __shared__ __align__(16) _Float16 Bs[4 * 4096];  // 32KB
  const int t = threadIdx.x;
  const int lane = t & 63, w = t >> 6;
  const int wm = w >> 1, wn = w & 1;
  const int m0 = blockIdx.x * 128, n0 = blockIdx.y * 128;
  const int lr = lane & 15, lk = lane >> 4;
  floatx4 acc[4][4];
  floatx4 zero = {0.f, 0.f, 0.f, 0.f};
#pragma unroll
  for (int mi = 0; mi < 4; ++mi)
#pragma unroll
    for (int ni = 0; ni < 4; ++ni) acc[mi][ni] = zero;

  auto stage = [&](int p, int kt) {   // 4 GLL per thread
    const int k0 = kt * 32;
#pragma unroll
    for (int j = 0; j < 2; ++j) {
      int cc = j * 256 + t;
      int row = cc >> 2, sl = cc & 3;
      int sg = sl ^ ((row >> 1) & 3);
      size_t ga = (size_t)(m0 + row) * 2048 + k0 + sg * 8;
      size_t gb = (size_t)(n0 + row) * 2048 + k0 + sg * 8;
      GLL(A2 + ga, &As[p * 4096 + cc * 8]);
      GLL(BT + gb, &Bs[p * 4096 + cc * 8]);
    }
  };
  auto compute = [&](int p) {
    half8 af[4], bf[4];
#pragma unroll
    for (int mi = 0; mi < 4; ++mi) {
      int row = wm * 64 + mi * 16 + lr;
      int sl = lk ^ ((row >> 1) & 3);
      af[mi] = *reinterpret_cast<const half8*>(&As[p * 4096 + row * 32 + sl * 8]);
    }
#pragma unroll
    for (int ni = 0; ni < 4; ++ni) {
      int row = wn * 64 + ni * 16 + lr;
      int sl = lk ^ ((row >> 1) & 3);
      bf[ni] = *reinterpret_cast<const half8*>(&Bs[p * 4096 + row * 32 + sl * 8]);
    }
#pragma unroll
    for (int mi = 0; mi < 4; ++mi)
#pragma unroll
      for (int ni = 0; ni < 4; ++ni)
        acc[mi][ni] = __builtin_amdgcn_mfma_f32_16x16x32_f16(af[mi], bf[ni], acc[mi][ni], 0, 0, 0);
  };

  stage(0, 0);
  stage(1, 1);
  stage(2, 2);
  for (int kt = 0; kt < 64; ++kt) {
    __builtin_amdgcn_sched_barrier(0);
    if (kt < 62) {
      asm volatile("s_waitcnt vmcnt(8)" ::: "memory");
    } else if (kt == 62) {
      asm volatile("s_waitcnt vmcnt(4)" ::: "memory");
    } else {
      asm volatile("s_waitcnt vmcnt(0)" ::: "memory");
    }
    __builtin_amdgcn_s_barrier();
    __builtin_amdgcn_sched_barrier(0);
    if (kt + 3 < 64) stage((kt + 3) & 3, kt + 3);
    compute(kt & 3);
  }

#pragma unroll
  for (int mi = 0; mi < 4; ++mi) {
#pragma unroll
    for (int ni = 0; ni < 4; ++ni) {
      int gn = n0 + wn * 64 + ni * 16 + lr;
      float bias = b_og[gn];
      int gmb = m0 + wm * 64 + mi * 16 + lk * 4;
#pragma unroll
      for (int j = 0; j < 4; ++j) {
        int gm = gmb + j;
        float v = acc[mi][ni][j] + bias;
        if (gn < 1024) {
          out[OUT_H_OFF + (size_t)gm * 1024 + gn] = tanhf(v);  // h_next
        } else {
          out[(size_t)gm * 1024 + (gn - 1024)] = v;            // y_t
        }
      }
    }
  }
}

extern "C" void kernel_launch(void* const* d_in, const int* in_sizes, int n_in,
                              void* d_out, int out_size, void* d_ws, size_t ws_size,
                              hipStream_t stream) {
  (void)in_sizes; (void)n_in; (void)out_size;
  const float* x_t    = (const float*)d_in[0];
  const float* h_prev = (const float*)d_in[1];
  const float* W_in   = (const float*)d_in[2];
  const float* b_in   = (const float*)d_in[3];
  const float* W_q    = (const float*)d_in[4];
  const float* b_q    = (const float*)d_in[5];
  const float* W_sel  = (const float*)d_in[6];
  const float* b_sel  = (const float*)d_in[7];
  const float* Wm_enc = (const float*)d_in[8];
  const float* theta  = (const float*)d_in[9];
  const float* Wm_dec = (const float*)d_in[10];
  const float* b_m    = (const float*)d_in[11];
  const float* W_og   = (const float*)d_in[12];
  const float* b_og   = (const float*)d_in[13];
  float* out = (float*)d_out;

  char* ws = (char*)d_ws;
  _Float16* A2          = (_Float16*)(ws + ((size_t)16 << 20));
  _Float16* BT          = (_Float16*)(ws + ((size_t)32 << 20));
  float* Wqs            = (float*)(ws + ((size_t)40 << 20));
  int* idx              = (int*)(ws + ((size_t)41 << 20));
  int* counter          = (int*)(ws + ((size_t)41 << 20) + 16384);
  int* list             = (int*)(ws + ((size_t)41 << 20) + 16384 + 64);
  _Float16* A1          = (_Float16*)(ws + ((size_t)42 << 20));
  _Float16* BTin        = (_Float16*)(ws + ((size_t)58 << 20));
  float* fix_scratch    = (float*)(ws + ((size_t)62 << 20));

  const bool use_mfma = ws_size >= ((size_t)82 << 20);

  hipLaunchKernelGGL(k_transpose, dim3(32, 32), dim3(256), 0, stream, W_og, BT);
  hipLaunchKernelGGL(k_wqs, dim3(257), dim3(256), 0, stream, W_q, b_q, W_sel, b_sel, Wqs);
  hipMemsetAsync(counter, 0, 4, stream);

  if (use_mfma) {
    hipLaunchKernelGGL(k_convA, dim3(2048), dim3(256), 0, stream, x_t, h_prev, A1);
    hipLaunchKernelGGL(k_convB, dim3(32, 16), dim3(256), 0, stream, W_in, BTin);
    hipLaunchKernelGGL(k_gemm1h, dim3(32, 16), dim3(256), 0, stream,
                       A1, BTin, b_in, A2);
    hipLaunchKernelGGL(k_argmax, dim3(512), dim3(256), 0, stream, A2, Wqs, idx, counter, list, TAU);
    hipLaunchKernelGGL(k_fixA3, dim3(16, 32), dim3(256), 0, stream,
                       x_t, h_prev, W_in, counter, list, fix_scratch);
    hipLaunchKernelGGL(k_fixB, dim3(FIX_CAP), dim3(256), 0, stream,
                       fix_scratch, b_in, Wqs, counter, list, idx);
  } else {
    hipLaunchKernelGGL(k_gemm1, dim3(32, 16), dim3(256), 0, stream, x_t, h_prev, W_in, b_in, A2);
    hipLaunchKernelGGL(k_argmax, dim3(512), dim3(256), 0, stream, A2, Wqs, idx, counter, list, 0.0f);
  }

  hipLaunchKernelGGL(k_mix, dim3(4096), dim3(256), 0, stream, A2, idx, Wm_enc, theta, Wm_dec, b_m, A2);
  hipLaunchKernelGGL(k_gemm4h, dim3(32, 16), dim3(256), 0, stream, A2, BT, b_og, out);
}